// Round 1
// baseline (244.613 us; speedup 1.0000x reference)
//
#include <hip/hip_runtime.h>
#include <hip/hip_cooperative_groups.h>

namespace cg = cooperative_groups;

#define CDIM 128          // feature dim C
#define FUSED_GRID 1024   // 4 blocks/CU x 256 CUs -> guaranteed co-resident
#define FUSED_BLOCK 256

// Native clang vectors — required by __builtin_nontemporal_load/store
typedef int            iv4 __attribute__((ext_vector_type(4)));
typedef float          fv4 __attribute__((ext_vector_type(4)));
typedef unsigned short sv4 __attribute__((ext_vector_type(4)));

__device__ __forceinline__ float sigmoidf_(float t) {
    return 1.0f / (1.0f + __expf(-t));
}
__device__ __forceinline__ unsigned short f2bf(float x) {   // round-to-nearest-even
    unsigned u = __float_as_uint(x);
    u += 0x7fffu + ((u >> 16) & 1u);
    return (unsigned short)(u >> 16);
}
__device__ __forceinline__ float bf2f(unsigned short h) {
    return __uint_as_float(((unsigned)h) << 16);
}

// ---------------- Fused persistent kernel: proj -> weights -> final --------
// Phase A: per-node projections, 32 lanes/node, grid-stride (~12 iters/thread).
// grid.sync() — cooperative-groups barrier (agent-scope fences give cross-XCD
//               visibility of sl/sr).
// Phase B: edge weights -> bf16 table. Each thread owns edge-quads i0 and i1
//          (statically indexed — no runtime-indexed reg arrays). The f32
//          sigmoid quads are KEPT IN REGISTERS across the next sync.
// grid.sync()
// Phase C: out = w_own(f32, from regs) * w_gathered(bf16 random gather).
//          Own-quad wbf re-read eliminated; precision improved (one bf16
//          rounding instead of two on the own factor).
__global__ __launch_bounds__(FUSED_BLOCK, 4)
void fused_kernel(const fv4* __restrict__ x4, const fv4* __restrict__ W4,
                  const int* __restrict__ row, const int* __restrict__ col,
                  const int* __restrict__ fri,
                  float* __restrict__ sl, float* __restrict__ sr,
                  unsigned short* __restrict__ wbf, float* __restrict__ out,
                  int n, int e) {
    cg::grid_group grid = cg::this_grid();
    const int gsz = FUSED_GRID * FUSED_BLOCK;              // 262144, mult of 32
    const int gid = blockIdx.x * FUSED_BLOCK + threadIdx.x;
    const int sub = gid & 31;                              // invariant under stride

    // ---- Phase A: projections ----
    const fv4 wl = W4[sub];        // W[0, 0:128]   = Wl  (L1-broadcast)
    const fv4 wr = W4[32 + sub];   // W[0, 128:256] = Wr
    const long long n32 = (long long)n * 32;
    for (long long t = gid; t < n32; t += gsz) {
        fv4 v = x4[t];             // t = node*32 + sub exactly; fully coalesced
        float pl = v.x * wl.x + v.y * wl.y + v.z * wl.z + v.w * wl.w;
        float pr = v.x * wr.x + v.y * wr.y + v.z * wr.z + v.w * wr.w;
#pragma unroll
        for (int off = 16; off; off >>= 1) {   // stays within 32-lane half
            pl += __shfl_xor(pl, off);
            pr += __shfl_xor(pr, off);
        }
        if (sub == 0) {
            int node = (int)(t >> 5);
            sl[node] = pl;
            sr[node] = pr;
        }
    }
    grid.sync();

    // ---- Phase B: edge weights -> bf16 table ----
    const int tv4 = (e + 3) >> 2;
    const int i0 = gid;
    const int i1 = gid + gsz;       // tv4=400000 < 2*gsz -> exactly <=2 quads/thread
    fv4 s0, s1;                     // f32 own-weights, live across the sync

    if (i0 < tv4) {
        int base = i0 * 4;
        if (base + 3 < e) {
            iv4 r = __builtin_nontemporal_load(((const iv4*)row) + i0);
            iv4 c = __builtin_nontemporal_load(((const iv4*)col) + i0);
            s0.x = sigmoidf_(sl[r.x] + sr[c.x]);
            s0.y = sigmoidf_(sl[r.y] + sr[c.y]);
            s0.z = sigmoidf_(sl[r.z] + sr[c.z]);
            s0.w = sigmoidf_(sl[r.w] + sr[c.w]);
            sv4 h;
            h.x = f2bf(s0.x); h.y = f2bf(s0.y); h.z = f2bf(s0.z); h.w = f2bf(s0.w);
            ((sv4*)wbf)[i0] = h;
        } else {
            for (int j = base; j < e; ++j)
                wbf[j] = f2bf(sigmoidf_(sl[row[j]] + sr[col[j]]));
        }
    }
    if (i1 < tv4) {
        int base = i1 * 4;
        if (base + 3 < e) {
            iv4 r = __builtin_nontemporal_load(((const iv4*)row) + i1);
            iv4 c = __builtin_nontemporal_load(((const iv4*)col) + i1);
            s1.x = sigmoidf_(sl[r.x] + sr[c.x]);
            s1.y = sigmoidf_(sl[r.y] + sr[c.y]);
            s1.z = sigmoidf_(sl[r.z] + sr[c.z]);
            s1.w = sigmoidf_(sl[r.w] + sr[c.w]);
            sv4 h;
            h.x = f2bf(s1.x); h.y = f2bf(s1.y); h.z = f2bf(s1.z); h.w = f2bf(s1.w);
            ((sv4*)wbf)[i1] = h;
        } else {
            for (int j = base; j < e; ++j)
                wbf[j] = f2bf(sigmoidf_(sl[row[j]] + sr[col[j]]));
        }
    }
    // safety net if e ever grows past 2 quads/thread (doesn't run at E=1.6M)
    for (int i = gid + 2 * gsz; i < tv4; i += gsz) {
        int base = i * 4;
        if (base + 3 < e) {
            iv4 r = __builtin_nontemporal_load(((const iv4*)row) + i);
            iv4 c = __builtin_nontemporal_load(((const iv4*)col) + i);
            sv4 h;
            h.x = f2bf(sigmoidf_(sl[r.x] + sr[c.x]));
            h.y = f2bf(sigmoidf_(sl[r.y] + sr[c.y]));
            h.z = f2bf(sigmoidf_(sl[r.z] + sr[c.z]));
            h.w = f2bf(sigmoidf_(sl[r.w] + sr[c.w]));
            ((sv4*)wbf)[i] = h;
        } else {
            for (int j = base; j < e; ++j)
                wbf[j] = f2bf(sigmoidf_(sl[row[j]] + sr[col[j]]));
        }
    }
    grid.sync();

    // ---- Phase C: gathered product ----
    if (i0 < tv4) {
        int base = i0 * 4;
        if (base + 3 < e) {          // same predicate as phase B -> s0 is valid
            iv4 f = __builtin_nontemporal_load(((const iv4*)fri) + i0);
            float b0 = bf2f(wbf[f.x]);   // 4 independent random gathers in flight
            float b1 = bf2f(wbf[f.y]);
            float b2 = bf2f(wbf[f.z]);
            float b3 = bf2f(wbf[f.w]);
            fv4 o;
            o.x = s0.x * b0; o.y = s0.y * b1; o.z = s0.z * b2; o.w = s0.w * b3;
            __builtin_nontemporal_store(o, ((fv4*)out) + i0);
        } else {
            for (int j = base; j < e; ++j)
                out[j] = bf2f(wbf[j]) * bf2f(wbf[fri[j]]);
        }
    }
    if (i1 < tv4) {
        int base = i1 * 4;
        if (base + 3 < e) {
            iv4 f = __builtin_nontemporal_load(((const iv4*)fri) + i1);
            float b0 = bf2f(wbf[f.x]);
            float b1 = bf2f(wbf[f.y]);
            float b2 = bf2f(wbf[f.z]);
            float b3 = bf2f(wbf[f.w]);
            fv4 o;
            o.x = s1.x * b0; o.y = s1.y * b1; o.z = s1.z * b2; o.w = s1.w * b3;
            __builtin_nontemporal_store(o, ((fv4*)out) + i1);
        } else {
            for (int j = base; j < e; ++j)
                out[j] = bf2f(wbf[j]) * bf2f(wbf[fri[j]]);
        }
    }
    for (int i = gid + 2 * gsz; i < tv4; i += gsz) {
        int base = i * 4;
        if (base + 3 < e) {
            iv4 f = __builtin_nontemporal_load(((const iv4*)fri) + i);
            sv4 h = ((const sv4*)wbf)[i];
            fv4 o;
            o.x = bf2f(h.x) * bf2f(wbf[f.x]);
            o.y = bf2f(h.y) * bf2f(wbf[f.y]);
            o.z = bf2f(h.z) * bf2f(wbf[f.z]);
            o.w = bf2f(h.w) * bf2f(wbf[f.w]);
            __builtin_nontemporal_store(o, ((fv4*)out) + i);
        } else {
            for (int j = base; j < e; ++j)
                out[j] = bf2f(wbf[j]) * bf2f(wbf[fri[j]]);
        }
    }
}

// ---------------- K1: per-node projections (fallback path) -----------------
__global__ void proj_kernel(const fv4* __restrict__ x4, const fv4* __restrict__ W4,
                            float* __restrict__ sl, float* __restrict__ sr, int n) {
    int gid  = blockIdx.x * blockDim.x + threadIdx.x;
    int node = gid >> 5;
    int sub  = gid & 31;
    if (node >= n) return;
    fv4 v  = x4[(size_t)node * 32 + sub];
    fv4 wl = W4[sub];
    fv4 wr = W4[32 + sub];
    float pl = v.x * wl.x + v.y * wl.y + v.z * wl.z + v.w * wl.w;
    float pr = v.x * wr.x + v.y * wr.y + v.z * wr.z + v.w * wr.w;
#pragma unroll
    for (int off = 16; off; off >>= 1) {
        pl += __shfl_xor(pl, off);
        pr += __shfl_xor(pr, off);
    }
    if (sub == 0) { sl[node] = pl; sr[node] = pr; }
}

// ---------------- K2: edge weights -> bf16 (fallback path) -----------------
__global__ __launch_bounds__(256)
void weights_bf_kernel(const int* __restrict__ row, const int* __restrict__ col,
                       const float* __restrict__ sl, const float* __restrict__ sr,
                       unsigned short* __restrict__ wbf, int e) {
    int i = blockIdx.x * blockDim.x + threadIdx.x;
    int base = i * 4;
    if (base + 3 < e) {
        iv4 r = __builtin_nontemporal_load(((const iv4*)row) + i);
        iv4 c = __builtin_nontemporal_load(((const iv4*)col) + i);
        sv4 h;
        h.x = f2bf(sigmoidf_(sl[r.x] + sr[c.x]));
        h.y = f2bf(sigmoidf_(sl[r.y] + sr[c.y]));
        h.z = f2bf(sigmoidf_(sl[r.z] + sr[c.z]));
        h.w = f2bf(sigmoidf_(sl[r.w] + sr[c.w]));
        ((sv4*)wbf)[i] = h;
    } else if (base < e) {
        for (int j = base; j < e; ++j)
            wbf[j] = f2bf(sigmoidf_(sl[row[j]] + sr[col[j]]));
    }
}

// ---------------- K3: gathered product (fallback path) ---------------------
__global__ __launch_bounds__(256)
void final4_kernel(const unsigned short* __restrict__ wbf,
                   const int* __restrict__ fri, float* __restrict__ out, int e) {
    int i = blockIdx.x * blockDim.x + threadIdx.x;
    int base = i * 4;
    if (base + 3 < e) {
        iv4 f = __builtin_nontemporal_load(((const iv4*)fri) + i);
        sv4 h = ((const sv4*)wbf)[i];
        float b0 = bf2f(wbf[f.x]);
        float b1 = bf2f(wbf[f.y]);
        float b2 = bf2f(wbf[f.z]);
        float b3 = bf2f(wbf[f.w]);
        fv4 o;
        o.x = bf2f(h.x) * b0;
        o.y = bf2f(h.y) * b1;
        o.z = bf2f(h.z) * b2;
        o.w = bf2f(h.w) * b3;
        __builtin_nontemporal_store(o, ((fv4*)out) + i);
    } else if (base < e) {
        for (int j = base; j < e; ++j)
            out[j] = bf2f(wbf[j]) * bf2f(wbf[fri[j]]);
    }
}

// ---------------- Fallbacks ------------------------------------------------
__global__ void recompute_kernel(const int* __restrict__ row, const int* __restrict__ col,
                                 const int* __restrict__ fri,
                                 const float* __restrict__ sl, const float* __restrict__ sr,
                                 float* __restrict__ out, int e) {
    int i = blockIdx.x * blockDim.x + threadIdx.x;
    if (i >= e) return;
    int f = fri[i];
    float wa = sigmoidf_(sl[row[i]] + sr[col[i]]);
    float wb = sigmoidf_(sl[row[f]] + sr[col[f]]);
    out[i] = wa * wb;
}

__global__ void naive_kernel(const float* __restrict__ x, const float* __restrict__ W,
                             const int* __restrict__ row, const int* __restrict__ col,
                             const int* __restrict__ fri, float* __restrict__ out, int e) {
    int gid  = blockIdx.x * blockDim.x + threadIdx.x;
    int edge = gid >> 6;
    int lane = gid & 63;
    if (edge >= e) return;
    int f = fri[edge];
    const float2* X = (const float2*)x;
    float2 wl = ((const float2*)W)[lane];
    float2 wr = ((const float2*)W)[64 + lane];
    float2 a1 = X[(size_t)row[edge] * 64 + lane];
    float2 b1 = X[(size_t)col[edge] * 64 + lane];
    float2 a2 = X[(size_t)row[f] * 64 + lane];
    float2 b2 = X[(size_t)col[f] * 64 + lane];
    float p1 = a1.x * wl.x + a1.y * wl.y + b1.x * wr.x + b1.y * wr.y;
    float p2 = a2.x * wl.x + a2.y * wl.y + b2.x * wr.x + b2.y * wr.y;
#pragma unroll
    for (int off = 32; off; off >>= 1) {
        p1 += __shfl_xor(p1, off);
        p2 += __shfl_xor(p2, off);
    }
    if (lane == 0) out[edge] = sigmoidf_(p1) * sigmoidf_(p2);
}

extern "C" void kernel_launch(void* const* d_in, const int* in_sizes, int n_in,
                              void* d_out, int out_size, void* d_ws, size_t ws_size,
                              hipStream_t stream) {
    const float* x   = (const float*)d_in[0];
    const int*   ei  = (const int*)d_in[1];
    const int*   fri = (const int*)d_in[2];
    const float* W   = (const float*)d_in[3];
    float* out = (float*)d_out;

    const int n = in_sizes[0] / CDIM;   // 100000 nodes
    const int e = in_sizes[2];          // 1600000 edges
    const int* row = ei;
    const int* col = ei + e;

    const size_t need_s  = (size_t)2 * n * sizeof(float);
    const size_t need_bf = need_s + (size_t)e * sizeof(unsigned short);

    float* sl = (float*)d_ws;
    float* sr = sl + n;

    const int BS = 256;
    const int tv4 = (e + 3) / 4;
    const long long proj_threads = (long long)n * 32;
    const int proj_grid = (int)((proj_threads + BS - 1) / BS);

    if (ws_size >= need_bf) {
        unsigned short* wbf = (unsigned short*)(sr + n);

        // --- cooperative fused path ---
        const fv4* x4p = (const fv4*)x;
        const fv4* W4p = (const fv4*)W;
        const int* rowp = row;
        const int* colp = col;
        const int* frip = fri;
        float* slp = sl;
        float* srp = sr;
        unsigned short* wbfp = wbf;
        float* outp = out;
        int nn = n, ee = e;
        void* kargs[] = {&x4p, &W4p, &rowp, &colp, &frip,
                         &slp, &srp, &wbfp, &outp, &nn, &ee};
        hipError_t err = hipLaunchCooperativeKernel(
            (const void*)fused_kernel, dim3(FUSED_GRID), dim3(FUSED_BLOCK),
            kargs, 0, stream);
        if (err != hipSuccess) {
            // proven 3-kernel fallback
            proj_kernel<<<proj_grid, BS, 0, stream>>>((const fv4*)x, (const fv4*)W, sl, sr, n);
            weights_bf_kernel<<<(tv4 + BS - 1) / BS, BS, 0, stream>>>(row, col, sl, sr, wbf, e);
            final4_kernel<<<(tv4 + BS - 1) / BS, BS, 0, stream>>>(wbf, fri, out, e);
        }
    } else if (ws_size >= need_s) {
        proj_kernel<<<proj_grid, BS, 0, stream>>>((const fv4*)x, (const fv4*)W, sl, sr, n);
        recompute_kernel<<<(e + BS - 1) / BS, BS, 0, stream>>>(row, col, fri, sl, sr, out, e);
    } else {
        long long t = (long long)e * 64;
        naive_kernel<<<(int)((t + BS - 1) / BS), BS, 0, stream>>>(x, W, row, col, fri, out, e);
    }
}

// Round 4
// 189.683 us; speedup vs baseline: 1.2896x; 1.2896x over previous
//
#include <hip/hip_runtime.h>

#define CDIM 128          // feature dim C
#define FUSED_GRID 1024   // 4 blocks/CU x 256 CUs -> co-resident (coop launch verifies)
#define FUSED_BLOCK 256

// Native clang vectors — required by __builtin_nontemporal_load/store
typedef int            iv4 __attribute__((ext_vector_type(4)));
typedef float          fv4 __attribute__((ext_vector_type(4)));
typedef unsigned short sv4 __attribute__((ext_vector_type(4)));

__device__ __forceinline__ float sigmoidf_(float t) {
    return 1.0f / (1.0f + __expf(-t));
}
__device__ __forceinline__ unsigned short f2bf(float x) {   // round-to-nearest-even
    unsigned u = __float_as_uint(x);
    u += 0x7fffu + ((u >> 16) & 1u);
    return (unsigned short)(u >> 16);
}
__device__ __forceinline__ float bf2f(unsigned short h) {
    return __uint_as_float(((unsigned)h) << 16);
}

// Agent-scope (MALL-coherent, cache-bypassing) access helpers.
#define AGT __HIP_MEMORY_SCOPE_AGENT
__device__ __forceinline__ float ald_f32(const float* p) {
    unsigned v = __hip_atomic_load((unsigned*)(void*)p, __ATOMIC_RELAXED, AGT);
    return __uint_as_float(v);
}
__device__ __forceinline__ void ast_f32(float* p, float x) {
    __hip_atomic_store((unsigned*)(void*)p, __float_as_uint(x), __ATOMIC_RELAXED, AGT);
}
__device__ __forceinline__ void ast_u64(unsigned long long* p, unsigned long long v) {
    __hip_atomic_store(p, v, __ATOMIC_RELAXED, AGT);
}
__device__ __forceinline__ unsigned long long ald_u64(const unsigned long long* p) {
    return __hip_atomic_load((unsigned long long*)(void*)p, __ATOMIC_RELAXED, AGT);
}
// bf16 gather from wbf via aligned 4B MALL load (index f in ushort units)
__device__ __forceinline__ float gath_bf(const unsigned short* wbf, int f) {
    unsigned v = __hip_atomic_load((unsigned*)(void*)((const unsigned*)(const void*)wbf + (f >> 1)),
                                   __ATOMIC_RELAXED, AGT);
    return bf2f((f & 1) ? (unsigned short)(v >> 16) : (unsigned short)v);
}

// ---------------- monotonic generation grid barrier ------------------------
// State lives in __device__ globals (module data segment): zero at .so load,
// NEVER touched by the workspace re-poison, never reset. Each round:
//   g = gen[k]; a = arrive[k]++;            (relaxed, agent -> MALL)
//   if last of round: gen[k]++;  else spin while gen[k]==g (relaxed, agent)
// gen only advances after all 1024 arrivals of THIS round (our own arrival is
// required), so early-pass is impossible; monotonicity makes missed wakeups
// impossible. __syncthreads before arrival drains every thread's MALL-bound
// data stores (vmcnt 0 precedes s_barrier), so data is at MALL before gen++.
__device__ int g_arrive[2];
__device__ int g_gen[2];

__device__ __forceinline__ void gridbar(int k) {
    __syncthreads();
    if (threadIdx.x == 0) {
        int g = __hip_atomic_load(&g_gen[k], __ATOMIC_RELAXED, AGT);
        int a = __hip_atomic_fetch_add(&g_arrive[k], 1, __ATOMIC_RELAXED, AGT);
        if ((a & (FUSED_GRID - 1)) == (FUSED_GRID - 1)) {
            __hip_atomic_fetch_add(&g_gen[k], 1, __ATOMIC_RELAXED, AGT);
        } else {
            int spins = 0;
            while (__hip_atomic_load(&g_gen[k], __ATOMIC_RELAXED, AGT) == g) {
                __builtin_amdgcn_s_sleep(4);
                if (++spins > 2000000) break;   // fail loud, not hang
            }
        }
    }
    __syncthreads();
}

// ---------------- Fused persistent kernel: proj -> bar -> weights -> bar -> final
__global__ __launch_bounds__(FUSED_BLOCK, 4)
void fused_kernel(const fv4* __restrict__ x4, const fv4* __restrict__ W4,
                  const int* __restrict__ row, const int* __restrict__ col,
                  const int* __restrict__ fri,
                  float* __restrict__ sl, float* __restrict__ sr,
                  unsigned short* __restrict__ wbf, float* __restrict__ out,
                  int n, int e) {
    const int gsz = FUSED_GRID * FUSED_BLOCK;              // 262144, mult of 32
    const int gid = blockIdx.x * FUSED_BLOCK + threadIdx.x;
    const int sub = gid & 31;                              // invariant under stride

    // ---- Phase A: per-node projections, 32 lanes/node ----
    // x/W are read-only inputs (never re-poisoned): plain cached loads.
    // sl/sr stores go agent-scope -> MALL (cross-XCD readers in phase B).
    const fv4 wl = W4[sub];        // W[0, 0:128]   = Wl
    const fv4 wr = W4[32 + sub];   // W[0, 128:256] = Wr
    const long long n32 = (long long)n * 32;
    for (long long t = gid; t < n32; t += gsz) {
        fv4 v = x4[t];             // t = node*32 + sub exactly; fully coalesced
        float pl = v.x * wl.x + v.y * wl.y + v.z * wl.z + v.w * wl.w;
        float pr = v.x * wr.x + v.y * wr.y + v.z * wr.z + v.w * wr.w;
#pragma unroll
        for (int off = 16; off; off >>= 1) {   // stays within 32-lane half
            pl += __shfl_xor(pl, off);
            pr += __shfl_xor(pr, off);
        }
        if (sub == 0) {
            int node = (int)(t >> 5);
            ast_f32(&sl[node], pl);
            ast_f32(&sr[node], pr);
        }
    }
    gridbar(0);

    // ---- Phase B: edge weights -> bf16 table (MALL loads + MALL store) ----
    const int tv4 = (e + 3) >> 2;
    const int i0 = gid;
    const int i1 = gid + gsz;       // tv4=400000 < 2*gsz -> exactly <=2 quads/thread
    fv4 s0, s1;                     // f32 own-weights, live across the barrier

    if (i0 < tv4) {
        int base = i0 * 4;
        if (base + 3 < e) {
            iv4 r = __builtin_nontemporal_load(((const iv4*)row) + i0);
            iv4 c = __builtin_nontemporal_load(((const iv4*)col) + i0);
            float a0 = ald_f32(&sl[r.x]), a1 = ald_f32(&sl[r.y]);
            float a2 = ald_f32(&sl[r.z]), a3 = ald_f32(&sl[r.w]);
            float b0 = ald_f32(&sr[c.x]), b1 = ald_f32(&sr[c.y]);
            float b2 = ald_f32(&sr[c.z]), b3 = ald_f32(&sr[c.w]);
            s0.x = sigmoidf_(a0 + b0); s0.y = sigmoidf_(a1 + b1);
            s0.z = sigmoidf_(a2 + b2); s0.w = sigmoidf_(a3 + b3);
            unsigned long long pk =  (unsigned long long)f2bf(s0.x)
                                  | ((unsigned long long)f2bf(s0.y) << 16)
                                  | ((unsigned long long)f2bf(s0.z) << 32)
                                  | ((unsigned long long)f2bf(s0.w) << 48);
            ast_u64(((unsigned long long*)wbf) + i0, pk);
        } else {                     // unreachable at e%4==0; kept for generality
            for (int j = base; j < e; ++j) {
                float w = sigmoidf_(ald_f32(&sl[row[j]]) + ald_f32(&sr[col[j]]));
                wbf[j] = f2bf(w);
            }
        }
    }
    if (i1 < tv4) {
        int base = i1 * 4;
        if (base + 3 < e) {
            iv4 r = __builtin_nontemporal_load(((const iv4*)row) + i1);
            iv4 c = __builtin_nontemporal_load(((const iv4*)col) + i1);
            float a0 = ald_f32(&sl[r.x]), a1 = ald_f32(&sl[r.y]);
            float a2 = ald_f32(&sl[r.z]), a3 = ald_f32(&sl[r.w]);
            float b0 = ald_f32(&sr[c.x]), b1 = ald_f32(&sr[c.y]);
            float b2 = ald_f32(&sr[c.z]), b3 = ald_f32(&sr[c.w]);
            s1.x = sigmoidf_(a0 + b0); s1.y = sigmoidf_(a1 + b1);
            s1.z = sigmoidf_(a2 + b2); s1.w = sigmoidf_(a3 + b3);
            unsigned long long pk =  (unsigned long long)f2bf(s1.x)
                                  | ((unsigned long long)f2bf(s1.y) << 16)
                                  | ((unsigned long long)f2bf(s1.z) << 32)
                                  | ((unsigned long long)f2bf(s1.w) << 48);
            ast_u64(((unsigned long long*)wbf) + i1, pk);
        } else {
            for (int j = base; j < e; ++j) {
                float w = sigmoidf_(ald_f32(&sl[row[j]]) + ald_f32(&sr[col[j]]));
                wbf[j] = f2bf(w);
            }
        }
    }
    // safety net if e ever grows past 2 quads/thread (doesn't run at E=1.6M)
    for (int i = gid + 2 * gsz; i < tv4; i += gsz) {
        int base = i * 4;
        if (base + 3 < e) {
            iv4 r = __builtin_nontemporal_load(((const iv4*)row) + i);
            iv4 c = __builtin_nontemporal_load(((const iv4*)col) + i);
            float w0 = sigmoidf_(ald_f32(&sl[r.x]) + ald_f32(&sr[c.x]));
            float w1 = sigmoidf_(ald_f32(&sl[r.y]) + ald_f32(&sr[c.y]));
            float w2 = sigmoidf_(ald_f32(&sl[r.z]) + ald_f32(&sr[c.z]));
            float w3 = sigmoidf_(ald_f32(&sl[r.w]) + ald_f32(&sr[c.w]));
            unsigned long long pk =  (unsigned long long)f2bf(w0)
                                  | ((unsigned long long)f2bf(w1) << 16)
                                  | ((unsigned long long)f2bf(w2) << 32)
                                  | ((unsigned long long)f2bf(w3) << 48);
            ast_u64(((unsigned long long*)wbf) + i, pk);
        } else {
            for (int j = base; j < e; ++j) {
                float w = sigmoidf_(ald_f32(&sl[row[j]]) + ald_f32(&sr[col[j]]));
                wbf[j] = f2bf(w);
            }
        }
    }
    gridbar(1);

    // ---- Phase C: gathered product (own weight from registers) ----
    if (i0 < tv4) {
        int base = i0 * 4;
        if (base + 3 < e) {          // same predicate as phase B -> s0 is valid
            iv4 f = __builtin_nontemporal_load(((const iv4*)fri) + i0);
            float b0 = gath_bf(wbf, f.x);   // 4 independent MALL gathers in flight
            float b1 = gath_bf(wbf, f.y);
            float b2 = gath_bf(wbf, f.z);
            float b3 = gath_bf(wbf, f.w);
            fv4 o;
            o.x = s0.x * b0; o.y = s0.y * b1; o.z = s0.z * b2; o.w = s0.w * b3;
            __builtin_nontemporal_store(o, ((fv4*)out) + i0);
        } else {
            for (int j = base; j < e; ++j)
                out[j] = gath_bf(wbf, j) * gath_bf(wbf, fri[j]);
        }
    }
    if (i1 < tv4) {
        int base = i1 * 4;
        if (base + 3 < e) {
            iv4 f = __builtin_nontemporal_load(((const iv4*)fri) + i1);
            float b0 = gath_bf(wbf, f.x);
            float b1 = gath_bf(wbf, f.y);
            float b2 = gath_bf(wbf, f.z);
            float b3 = gath_bf(wbf, f.w);
            fv4 o;
            o.x = s1.x * b0; o.y = s1.y * b1; o.z = s1.z * b2; o.w = s1.w * b3;
            __builtin_nontemporal_store(o, ((fv4*)out) + i1);
        } else {
            for (int j = base; j < e; ++j)
                out[j] = gath_bf(wbf, j) * gath_bf(wbf, fri[j]);
        }
    }
    for (int i = gid + 2 * gsz; i < tv4; i += gsz) {
        int base = i * 4;
        if (base + 3 < e) {
            iv4 f = __builtin_nontemporal_load(((const iv4*)fri) + i);
            unsigned long long hv = ald_u64(((const unsigned long long*)wbf) + i);
            fv4 o;
            o.x = bf2f((unsigned short)(hv      )) * gath_bf(wbf, f.x);
            o.y = bf2f((unsigned short)(hv >> 16)) * gath_bf(wbf, f.y);
            o.z = bf2f((unsigned short)(hv >> 32)) * gath_bf(wbf, f.z);
            o.w = bf2f((unsigned short)(hv >> 48)) * gath_bf(wbf, f.w);
            __builtin_nontemporal_store(o, ((fv4*)out) + i);
        } else {
            for (int j = base; j < e; ++j)
                out[j] = gath_bf(wbf, j) * gath_bf(wbf, fri[j]);
        }
    }
}

// ---------------- K1: per-node projections (fallback path) -----------------
__global__ void proj_kernel(const fv4* __restrict__ x4, const fv4* __restrict__ W4,
                            float* __restrict__ sl, float* __restrict__ sr, int n) {
    int gid  = blockIdx.x * blockDim.x + threadIdx.x;
    int node = gid >> 5;
    int sub  = gid & 31;
    if (node >= n) return;
    fv4 v  = x4[(size_t)node * 32 + sub];
    fv4 wl = W4[sub];
    fv4 wr = W4[32 + sub];
    float pl = v.x * wl.x + v.y * wl.y + v.z * wl.z + v.w * wl.w;
    float pr = v.x * wr.x + v.y * wr.y + v.z * wr.z + v.w * wr.w;
#pragma unroll
    for (int off = 16; off; off >>= 1) {
        pl += __shfl_xor(pl, off);
        pr += __shfl_xor(pr, off);
    }
    if (sub == 0) { sl[node] = pl; sr[node] = pr; }
}

// ---------------- K2: edge weights -> bf16 (fallback path) -----------------
__global__ __launch_bounds__(256)
void weights_bf_kernel(const int* __restrict__ row, const int* __restrict__ col,
                       const float* __restrict__ sl, const float* __restrict__ sr,
                       unsigned short* __restrict__ wbf, int e) {
    int i = blockIdx.x * blockDim.x + threadIdx.x;
    int base = i * 4;
    if (base + 3 < e) {
        iv4 r = __builtin_nontemporal_load(((const iv4*)row) + i);
        iv4 c = __builtin_nontemporal_load(((const iv4*)col) + i);
        sv4 h;
        h.x = f2bf(sigmoidf_(sl[r.x] + sr[c.x]));
        h.y = f2bf(sigmoidf_(sl[r.y] + sr[c.y]));
        h.z = f2bf(sigmoidf_(sl[r.z] + sr[c.z]));
        h.w = f2bf(sigmoidf_(sl[r.w] + sr[c.w]));
        ((sv4*)wbf)[i] = h;
    } else if (base < e) {
        for (int j = base; j < e; ++j)
            wbf[j] = f2bf(sigmoidf_(sl[row[j]] + sr[col[j]]));
    }
}

// ---------------- K3: gathered product (fallback path) ---------------------
__global__ __launch_bounds__(256)
void final4_kernel(const unsigned short* __restrict__ wbf,
                   const int* __restrict__ fri, float* __restrict__ out, int e) {
    int i = blockIdx.x * blockDim.x + threadIdx.x;
    int base = i * 4;
    if (base + 3 < e) {
        iv4 f = __builtin_nontemporal_load(((const iv4*)fri) + i);
        sv4 h = ((const sv4*)wbf)[i];
        float b0 = bf2f(wbf[f.x]);
        float b1 = bf2f(wbf[f.y]);
        float b2 = bf2f(wbf[f.z]);
        float b3 = bf2f(wbf[f.w]);
        fv4 o;
        o.x = bf2f(h.x) * b0;
        o.y = bf2f(h.y) * b1;
        o.z = bf2f(h.z) * b2;
        o.w = bf2f(h.w) * b3;
        __builtin_nontemporal_store(o, ((fv4*)out) + i);
    } else if (base < e) {
        for (int j = base; j < e; ++j)
            out[j] = bf2f(wbf[j]) * bf2f(wbf[fri[j]]);
    }
}

// ---------------- Fallbacks ------------------------------------------------
__global__ void recompute_kernel(const int* __restrict__ row, const int* __restrict__ col,
                                 const int* __restrict__ fri,
                                 const float* __restrict__ sl, const float* __restrict__ sr,
                                 float* __restrict__ out, int e) {
    int i = blockIdx.x * blockDim.x + threadIdx.x;
    if (i >= e) return;
    int f = fri[i];
    float wa = sigmoidf_(sl[row[i]] + sr[col[i]]);
    float wb = sigmoidf_(sl[row[f]] + sr[col[f]]);
    out[i] = wa * wb;
}

__global__ void naive_kernel(const float* __restrict__ x, const float* __restrict__ W,
                             const int* __restrict__ row, const int* __restrict__ col,
                             const int* __restrict__ fri, float* __restrict__ out, int e) {
    int gid  = blockIdx.x * blockDim.x + threadIdx.x;
    int edge = gid >> 6;
    int lane = gid & 63;
    if (edge >= e) return;
    int f = fri[edge];
    const float2* X = (const float2*)x;
    float2 wl = ((const float2*)W)[lane];
    float2 wr = ((const float2*)W)[64 + lane];
    float2 a1 = X[(size_t)row[edge] * 64 + lane];
    float2 b1 = X[(size_t)col[edge] * 64 + lane];
    float2 a2 = X[(size_t)row[f] * 64 + lane];
    float2 b2 = X[(size_t)col[f] * 64 + lane];
    float p1 = a1.x * wl.x + a1.y * wl.y + b1.x * wr.x + b1.y * wr.y;
    float p2 = a2.x * wl.x + a2.y * wl.y + b2.x * wr.x + b2.y * wr.y;
#pragma unroll
    for (int off = 32; off; off >>= 1) {
        p1 += __shfl_xor(p1, off);
        p2 += __shfl_xor(p2, off);
    }
    if (lane == 0) out[edge] = sigmoidf_(p1) * sigmoidf_(p2);
}

extern "C" void kernel_launch(void* const* d_in, const int* in_sizes, int n_in,
                              void* d_out, int out_size, void* d_ws, size_t ws_size,
                              hipStream_t stream) {
    const float* x   = (const float*)d_in[0];
    const int*   ei  = (const int*)d_in[1];
    const int*   fri = (const int*)d_in[2];
    const float* W   = (const float*)d_in[3];
    float* out = (float*)d_out;

    const int n = in_sizes[0] / CDIM;   // 100000 nodes
    const int e = in_sizes[2];          // 1600000 edges
    const int* row = ei;
    const int* col = ei + e;

    const size_t need_s  = (size_t)2 * n * sizeof(float);
    const size_t need_bf = need_s + (size_t)e * sizeof(unsigned short);

    float* sl = (float*)d_ws;
    float* sr = sl + n;

    const int BS = 256;
    const int tv4 = (e + 3) / 4;
    const long long proj_threads = (long long)n * 32;
    const int proj_grid = (int)((proj_threads + BS - 1) / BS);

    if (ws_size >= need_bf) {
        unsigned short* wbf = (unsigned short*)(sr + n);

        const fv4* x4p = (const fv4*)x;
        const fv4* W4p = (const fv4*)W;
        const int* rowp = row;
        const int* colp = col;
        const int* frip = fri;
        float* slp = sl;
        float* srp = sr;
        unsigned short* wbfp = wbf;
        float* outp = out;
        int nn = n, ee = e;
        void* kargs[] = {&x4p, &W4p, &rowp, &colp, &frip,
                         &slp, &srp, &wbfp, &outp, &nn, &ee};
        hipError_t err = hipLaunchCooperativeKernel(
            (const void*)fused_kernel, dim3(FUSED_GRID), dim3(FUSED_BLOCK),
            kargs, 0, stream);
        if (err != hipSuccess) {
            // proven 3-kernel fallback
            proj_kernel<<<proj_grid, BS, 0, stream>>>((const fv4*)x, (const fv4*)W, sl, sr, n);
            weights_bf_kernel<<<(tv4 + BS - 1) / BS, BS, 0, stream>>>(row, col, sl, sr, wbf, e);
            final4_kernel<<<(tv4 + BS - 1) / BS, BS, 0, stream>>>(wbf, fri, out, e);
        }
    } else if (ws_size >= need_s) {
        proj_kernel<<<proj_grid, BS, 0, stream>>>((const fv4*)x, (const fv4*)W, sl, sr, n);
        recompute_kernel<<<(e + BS - 1) / BS, BS, 0, stream>>>(row, col, fri, sl, sr, out, e);
    } else {
        long long t = (long long)e * 64;
        naive_kernel<<<(int)((t + BS - 1) / BS), BS, 0, stream>>>(x, W, row, col, fri, out, e);
    }
}

// Round 5
// 184.356 us; speedup vs baseline: 1.3268x; 1.0289x over previous
//
#include <hip/hip_runtime.h>

#define CDIM 128          // feature dim C
#define FUSED_GRID 1024   // 4 blocks/CU x 256 CUs -> co-resident (coop launch verifies)
#define FUSED_BLOCK 256

// Native clang vectors — required by __builtin_nontemporal_load/store
typedef int            iv4 __attribute__((ext_vector_type(4)));
typedef float          fv4 __attribute__((ext_vector_type(4)));
typedef unsigned short sv4 __attribute__((ext_vector_type(4)));

__device__ __forceinline__ float sigmoidf_(float t) {
    return 1.0f / (1.0f + __expf(-t));
}
__device__ __forceinline__ unsigned short f2bf(float x) {   // round-to-nearest-even
    unsigned u = __float_as_uint(x);
    u += 0x7fffu + ((u >> 16) & 1u);
    return (unsigned short)(u >> 16);
}
__device__ __forceinline__ float bf2f(unsigned short h) {
    return __uint_as_float(((unsigned)h) << 16);
}

// Agent-scope (MALL-coherent, cache-bypassing) STORE helpers. Only stores are
// MALL-direct: readers use cached loads (L2 starts invalidated each dispatch,
// and sl/sr/wbf are never read before their producing barrier, so no XCD L2
// can hold a stale line at first read — same coherence argument that makes
// the 3-kernel pipeline correct).
#define AGT __HIP_MEMORY_SCOPE_AGENT
__device__ __forceinline__ void ast_f32(float* p, float x) {
    __hip_atomic_store((unsigned*)(void*)p, __float_as_uint(x), __ATOMIC_RELAXED, AGT);
}
__device__ __forceinline__ void ast_u64(unsigned long long* p, unsigned long long v) {
    __hip_atomic_store(p, v, __ATOMIC_RELAXED, AGT);
}

// ---------------- monotonic generation grid barrier ------------------------
// State lives in __device__ globals (module data segment): zero at .so load,
// NEVER touched by the workspace re-poison, never reset. Each round:
//   g = gen[k]; a = arrive[k]++;            (relaxed, agent -> MALL)
//   if last of round: gen[k]++;  else spin while gen[k]==g (relaxed, agent)
// gen only advances after all 1024 arrivals of THIS round, so early-pass is
// impossible; monotonicity makes missed wakeups impossible. __syncthreads
// before arrival drains every thread's MALL-bound data stores (vmcnt 0
// precedes s_barrier), so data is at MALL before gen++.   [proven in R4]
__device__ int g_arrive[2];
__device__ int g_gen[2];

__device__ __forceinline__ void gridbar(int k) {
    __syncthreads();
    if (threadIdx.x == 0) {
        int g = __hip_atomic_load(&g_gen[k], __ATOMIC_RELAXED, AGT);
        int a = __hip_atomic_fetch_add(&g_arrive[k], 1, __ATOMIC_RELAXED, AGT);
        if ((a & (FUSED_GRID - 1)) == (FUSED_GRID - 1)) {
            __hip_atomic_fetch_add(&g_gen[k], 1, __ATOMIC_RELAXED, AGT);
        } else {
            int spins = 0;
            while (__hip_atomic_load(&g_gen[k], __ATOMIC_RELAXED, AGT) == g) {
                __builtin_amdgcn_s_sleep(4);
                if (++spins > 2000000) break;   // fail loud, not hang
            }
        }
    }
    __syncthreads();
}

// ---------------- Fused persistent kernel: proj -> bar -> weights -> bar -> final
__global__ __launch_bounds__(FUSED_BLOCK, 4)
void fused_kernel(const fv4* __restrict__ x4, const fv4* __restrict__ W4,
                  const int* __restrict__ row, const int* __restrict__ col,
                  const int* __restrict__ fri,
                  float* __restrict__ sl, float* __restrict__ sr,
                  unsigned short* __restrict__ wbf, float* __restrict__ out,
                  int n, int e) {
    const int gsz = FUSED_GRID * FUSED_BLOCK;              // 262144, mult of 32
    const int gid = blockIdx.x * FUSED_BLOCK + threadIdx.x;
    const int sub = gid & 31;                              // invariant under stride

    // ---- Phase A: per-node projections, 32 lanes/node ----
    // x/W read-only inputs: plain cached loads. sl/sr stores MALL-direct.
    const fv4 wl = W4[sub];        // W[0, 0:128]   = Wl
    const fv4 wr = W4[32 + sub];   // W[0, 128:256] = Wr
    const long long n32 = (long long)n * 32;
    for (long long t = gid; t < n32; t += gsz) {
        fv4 v = x4[t];             // t = node*32 + sub exactly; fully coalesced
        float pl = v.x * wl.x + v.y * wl.y + v.z * wl.z + v.w * wl.w;
        float pr = v.x * wr.x + v.y * wr.y + v.z * wr.z + v.w * wr.w;
#pragma unroll
        for (int off = 16; off; off >>= 1) {   // stays within 32-lane half
            pl += __shfl_xor(pl, off);
            pr += __shfl_xor(pr, off);
        }
        if (sub == 0) {
            int node = (int)(t >> 5);
            ast_f32(&sl[node], pl);
            ast_f32(&sr[node], pr);
        }
    }
    gridbar(0);

    // ---- Phase B: edge weights -> bf16 table ----
    // sl/sr gathers CACHED (first touch miss-to-MALL, then L2-resident 800KB).
    // wbf store MALL-direct (readers are cross-XCD in phase C).
    const int tv4 = (e + 3) >> 2;
    const int i0 = gid;
    const int i1 = gid + gsz;       // tv4=400000 < 2*gsz -> exactly <=2 quads/thread
    fv4 s0, s1;                     // f32 own-weights, live across the barrier

    if (i0 < tv4) {
        int base = i0 * 4;
        if (base + 3 < e) {
            iv4 r = __builtin_nontemporal_load(((const iv4*)row) + i0);
            iv4 c = __builtin_nontemporal_load(((const iv4*)col) + i0);
            s0.x = sigmoidf_(sl[r.x] + sr[c.x]);
            s0.y = sigmoidf_(sl[r.y] + sr[c.y]);
            s0.z = sigmoidf_(sl[r.z] + sr[c.z]);
            s0.w = sigmoidf_(sl[r.w] + sr[c.w]);
            unsigned long long pk =  (unsigned long long)f2bf(s0.x)
                                  | ((unsigned long long)f2bf(s0.y) << 16)
                                  | ((unsigned long long)f2bf(s0.z) << 32)
                                  | ((unsigned long long)f2bf(s0.w) << 48);
            ast_u64(((unsigned long long*)wbf) + i0, pk);
        } else {                     // unreachable at e%4==0; kept for generality
            for (int j = base; j < e; ++j)
                wbf[j] = f2bf(sigmoidf_(sl[row[j]] + sr[col[j]]));
        }
    }
    if (i1 < tv4) {
        int base = i1 * 4;
        if (base + 3 < e) {
            iv4 r = __builtin_nontemporal_load(((const iv4*)row) + i1);
            iv4 c = __builtin_nontemporal_load(((const iv4*)col) + i1);
            s1.x = sigmoidf_(sl[r.x] + sr[c.x]);
            s1.y = sigmoidf_(sl[r.y] + sr[c.y]);
            s1.z = sigmoidf_(sl[r.z] + sr[c.z]);
            s1.w = sigmoidf_(sl[r.w] + sr[c.w]);
            unsigned long long pk =  (unsigned long long)f2bf(s1.x)
                                  | ((unsigned long long)f2bf(s1.y) << 16)
                                  | ((unsigned long long)f2bf(s1.z) << 32)
                                  | ((unsigned long long)f2bf(s1.w) << 48);
            ast_u64(((unsigned long long*)wbf) + i1, pk);
        } else {
            for (int j = base; j < e; ++j)
                wbf[j] = f2bf(sigmoidf_(sl[row[j]] + sr[col[j]]));
        }
    }
    // safety net if e ever grows past 2 quads/thread (doesn't run at E=1.6M)
    for (int i = gid + 2 * gsz; i < tv4; i += gsz) {
        int base = i * 4;
        if (base + 3 < e) {
            iv4 r = __builtin_nontemporal_load(((const iv4*)row) + i);
            iv4 c = __builtin_nontemporal_load(((const iv4*)col) + i);
            unsigned long long pk =
                  (unsigned long long)f2bf(sigmoidf_(sl[r.x] + sr[c.x]))
                | ((unsigned long long)f2bf(sigmoidf_(sl[r.y] + sr[c.y])) << 16)
                | ((unsigned long long)f2bf(sigmoidf_(sl[r.z] + sr[c.z])) << 32)
                | ((unsigned long long)f2bf(sigmoidf_(sl[r.w] + sr[c.w])) << 48);
            ast_u64(((unsigned long long*)wbf) + i, pk);
        } else {
            for (int j = base; j < e; ++j)
                wbf[j] = f2bf(sigmoidf_(sl[row[j]] + sr[col[j]]));
        }
    }
    gridbar(1);

    // ---- Phase C: gathered product (own weight from registers) ----
    // wbf gathers CACHED (3.2MB table, L2/MALL-resident).
    if (i0 < tv4) {
        int base = i0 * 4;
        if (base + 3 < e) {          // same predicate as phase B -> s0 is valid
            iv4 f = __builtin_nontemporal_load(((const iv4*)fri) + i0);
            float b0 = bf2f(wbf[f.x]);   // 4 independent random gathers in flight
            float b1 = bf2f(wbf[f.y]);
            float b2 = bf2f(wbf[f.z]);
            float b3 = bf2f(wbf[f.w]);
            fv4 o;
            o.x = s0.x * b0; o.y = s0.y * b1; o.z = s0.z * b2; o.w = s0.w * b3;
            __builtin_nontemporal_store(o, ((fv4*)out) + i0);
        } else {
            for (int j = base; j < e; ++j)
                out[j] = bf2f(wbf[j]) * bf2f(wbf[fri[j]]);
        }
    }
    if (i1 < tv4) {
        int base = i1 * 4;
        if (base + 3 < e) {
            iv4 f = __builtin_nontemporal_load(((const iv4*)fri) + i1);
            float b0 = bf2f(wbf[f.x]);
            float b1 = bf2f(wbf[f.y]);
            float b2 = bf2f(wbf[f.z]);
            float b3 = bf2f(wbf[f.w]);
            fv4 o;
            o.x = s1.x * b0; o.y = s1.y * b1; o.z = s1.z * b2; o.w = s1.w * b3;
            __builtin_nontemporal_store(o, ((fv4*)out) + i1);
        } else {
            for (int j = base; j < e; ++j)
                out[j] = bf2f(wbf[j]) * bf2f(wbf[fri[j]]);
        }
    }
    for (int i = gid + 2 * gsz; i < tv4; i += gsz) {
        int base = i * 4;
        if (base + 3 < e) {
            iv4 f = __builtin_nontemporal_load(((const iv4*)fri) + i);
            sv4 h = ((const sv4*)wbf)[i];
            fv4 o;
            o.x = bf2f(h.x) * bf2f(wbf[f.x]);
            o.y = bf2f(h.y) * bf2f(wbf[f.y]);
            o.z = bf2f(h.z) * bf2f(wbf[f.z]);
            o.w = bf2f(h.w) * bf2f(wbf[f.w]);
            __builtin_nontemporal_store(o, ((fv4*)out) + i);
        } else {
            for (int j = base; j < e; ++j)
                out[j] = bf2f(wbf[j]) * bf2f(wbf[fri[j]]);
        }
    }
}

// ---------------- K1: per-node projections (fallback path) -----------------
__global__ void proj_kernel(const fv4* __restrict__ x4, const fv4* __restrict__ W4,
                            float* __restrict__ sl, float* __restrict__ sr, int n) {
    int gid  = blockIdx.x * blockDim.x + threadIdx.x;
    int node = gid >> 5;
    int sub  = gid & 31;
    if (node >= n) return;
    fv4 v  = x4[(size_t)node * 32 + sub];
    fv4 wl = W4[sub];
    fv4 wr = W4[32 + sub];
    float pl = v.x * wl.x + v.y * wl.y + v.z * wl.z + v.w * wl.w;
    float pr = v.x * wr.x + v.y * wr.y + v.z * wr.z + v.w * wr.w;
#pragma unroll
    for (int off = 16; off; off >>= 1) {
        pl += __shfl_xor(pl, off);
        pr += __shfl_xor(pr, off);
    }
    if (sub == 0) { sl[node] = pl; sr[node] = pr; }
}

// ---------------- K2: edge weights -> bf16 (fallback path) -----------------
__global__ __launch_bounds__(256)
void weights_bf_kernel(const int* __restrict__ row, const int* __restrict__ col,
                       const float* __restrict__ sl, const float* __restrict__ sr,
                       unsigned short* __restrict__ wbf, int e) {
    int i = blockIdx.x * blockDim.x + threadIdx.x;
    int base = i * 4;
    if (base + 3 < e) {
        iv4 r = __builtin_nontemporal_load(((const iv4*)row) + i);
        iv4 c = __builtin_nontemporal_load(((const iv4*)col) + i);
        sv4 h;
        h.x = f2bf(sigmoidf_(sl[r.x] + sr[c.x]));
        h.y = f2bf(sigmoidf_(sl[r.y] + sr[c.y]));
        h.z = f2bf(sigmoidf_(sl[r.z] + sr[c.z]));
        h.w = f2bf(sigmoidf_(sl[r.w] + sr[c.w]));
        ((sv4*)wbf)[i] = h;
    } else if (base < e) {
        for (int j = base; j < e; ++j)
            wbf[j] = f2bf(sigmoidf_(sl[row[j]] + sr[col[j]]));
    }
}

// ---------------- K3: gathered product (fallback path) ---------------------
__global__ __launch_bounds__(256)
void final4_kernel(const unsigned short* __restrict__ wbf,
                   const int* __restrict__ fri, float* __restrict__ out, int e) {
    int i = blockIdx.x * blockDim.x + threadIdx.x;
    int base = i * 4;
    if (base + 3 < e) {
        iv4 f = __builtin_nontemporal_load(((const iv4*)fri) + i);
        sv4 h = ((const sv4*)wbf)[i];
        float b0 = bf2f(wbf[f.x]);
        float b1 = bf2f(wbf[f.y]);
        float b2 = bf2f(wbf[f.z]);
        float b3 = bf2f(wbf[f.w]);
        fv4 o;
        o.x = bf2f(h.x) * b0;
        o.y = bf2f(h.y) * b1;
        o.z = bf2f(h.z) * b2;
        o.w = bf2f(h.w) * b3;
        __builtin_nontemporal_store(o, ((fv4*)out) + i);
    } else if (base < e) {
        for (int j = base; j < e; ++j)
            out[j] = bf2f(wbf[j]) * bf2f(wbf[fri[j]]);
    }
}

// ---------------- Fallbacks ------------------------------------------------
__global__ void recompute_kernel(const int* __restrict__ row, const int* __restrict__ col,
                                 const int* __restrict__ fri,
                                 const float* __restrict__ sl, const float* __restrict__ sr,
                                 float* __restrict__ out, int e) {
    int i = blockIdx.x * blockDim.x + threadIdx.x;
    if (i >= e) return;
    int f = fri[i];
    float wa = sigmoidf_(sl[row[i]] + sr[col[i]]);
    float wb = sigmoidf_(sl[row[f]] + sr[col[f]]);
    out[i] = wa * wb;
}

__global__ void naive_kernel(const float* __restrict__ x, const float* __restrict__ W,
                             const int* __restrict__ row, const int* __restrict__ col,
                             const int* __restrict__ fri, float* __restrict__ out, int e) {
    int gid  = blockIdx.x * blockDim.x + threadIdx.x;
    int edge = gid >> 6;
    int lane = gid & 63;
    if (edge >= e) return;
    int f = fri[edge];
    const float2* X = (const float2*)x;
    float2 wl = ((const float2*)W)[lane];
    float2 wr = ((const float2*)W)[64 + lane];
    float2 a1 = X[(size_t)row[edge] * 64 + lane];
    float2 b1 = X[(size_t)col[edge] * 64 + lane];
    float2 a2 = X[(size_t)row[f] * 64 + lane];
    float2 b2 = X[(size_t)col[f] * 64 + lane];
    float p1 = a1.x * wl.x + a1.y * wl.y + b1.x * wr.x + b1.y * wr.y;
    float p2 = a2.x * wl.x + a2.y * wl.y + b2.x * wr.x + b2.y * wr.y;
#pragma unroll
    for (int off = 32; off; off >>= 1) {
        p1 += __shfl_xor(p1, off);
        p2 += __shfl_xor(p2, off);
    }
    if (lane == 0) out[edge] = sigmoidf_(p1) * sigmoidf_(p2);
}

extern "C" void kernel_launch(void* const* d_in, const int* in_sizes, int n_in,
                              void* d_out, int out_size, void* d_ws, size_t ws_size,
                              hipStream_t stream) {
    const float* x   = (const float*)d_in[0];
    const int*   ei  = (const int*)d_in[1];
    const int*   fri = (const int*)d_in[2];
    const float* W   = (const float*)d_in[3];
    float* out = (float*)d_out;

    const int n = in_sizes[0] / CDIM;   // 100000 nodes
    const int e = in_sizes[2];          // 1600000 edges
    const int* row = ei;
    const int* col = ei + e;

    const size_t need_s  = (size_t)2 * n * sizeof(float);
    const size_t need_bf = need_s + (size_t)e * sizeof(unsigned short);

    float* sl = (float*)d_ws;
    float* sr = sl + n;

    const int BS = 256;
    const int tv4 = (e + 3) / 4;
    const long long proj_threads = (long long)n * 32;
    const int proj_grid = (int)((proj_threads + BS - 1) / BS);

    if (ws_size >= need_bf) {
        unsigned short* wbf = (unsigned short*)(sr + n);

        const fv4* x4p = (const fv4*)x;
        const fv4* W4p = (const fv4*)W;
        const int* rowp = row;
        const int* colp = col;
        const int* frip = fri;
        float* slp = sl;
        float* srp = sr;
        unsigned short* wbfp = wbf;
        float* outp = out;
        int nn = n, ee = e;
        void* kargs[] = {&x4p, &W4p, &rowp, &colp, &frip,
                         &slp, &srp, &wbfp, &outp, &nn, &ee};
        hipError_t err = hipLaunchCooperativeKernel(
            (const void*)fused_kernel, dim3(FUSED_GRID), dim3(FUSED_BLOCK),
            kargs, 0, stream);
        if (err != hipSuccess) {
            // proven 3-kernel fallback
            proj_kernel<<<proj_grid, BS, 0, stream>>>((const fv4*)x, (const fv4*)W, sl, sr, n);
            weights_bf_kernel<<<(tv4 + BS - 1) / BS, BS, 0, stream>>>(row, col, sl, sr, wbf, e);
            final4_kernel<<<(tv4 + BS - 1) / BS, BS, 0, stream>>>(wbf, fri, out, e);
        }
    } else if (ws_size >= need_s) {
        proj_kernel<<<proj_grid, BS, 0, stream>>>((const fv4*)x, (const fv4*)W, sl, sr, n);
        recompute_kernel<<<(e + BS - 1) / BS, BS, 0, stream>>>(row, col, fri, sl, sr, out, e);
    } else {
        long long t = (long long)e * 64;
        naive_kernel<<<(int)((t + BS - 1) / BS), BS, 0, stream>>>(x, W, row, col, fri, out, e);
    }
}

// Round 6
// 72.057 us; speedup vs baseline: 3.3947x; 2.5585x over previous
//
#include <hip/hip_runtime.h>

#define CDIM 128          // feature dim C
#define FUSED_GRID 256    // 1 block/CU on 256 CUs -> co-resident (coop launch verifies)
#define FUSED_BLOCK 1024  // same total threads as before: 256*1024 = 262144

// Native clang vectors — required by __builtin_nontemporal_load/store
typedef int            iv4 __attribute__((ext_vector_type(4)));
typedef float          fv4 __attribute__((ext_vector_type(4)));
typedef unsigned short sv4 __attribute__((ext_vector_type(4)));

__device__ __forceinline__ float sigmoidf_(float t) {
    return 1.0f / (1.0f + __expf(-t));
}
__device__ __forceinline__ unsigned short f2bf(float x) {   // round-to-nearest-even
    unsigned u = __float_as_uint(x);
    u += 0x7fffu + ((u >> 16) & 1u);
    return (unsigned short)(u >> 16);
}
__device__ __forceinline__ float bf2f(unsigned short h) {
    return __uint_as_float(((unsigned)h) << 16);
}

// Agent-scope (MALL-coherent, cache-bypassing) STORE helpers. Only stores are
// MALL-direct: readers use cached loads (L2 starts invalidated each dispatch,
// and sl/sr/wbf are never read before their producing barrier, so no XCD L2
// can hold a stale line at first read).                       [proven R4/R5]
#define AGT __HIP_MEMORY_SCOPE_AGENT
__device__ __forceinline__ void ast_f32(float* p, float x) {
    __hip_atomic_store((unsigned*)(void*)p, __float_as_uint(x), __ATOMIC_RELAXED, AGT);
}
__device__ __forceinline__ void ast_u64(unsigned long long* p, unsigned long long v) {
    __hip_atomic_store(p, v, __ATOMIC_RELAXED, AGT);
}

// ---------------- monotonic generation grid barrier, contention-engineered --
// Logic identical to R4/R5 (proven across replays): monotonic counters in
// __device__ globals (zero at .so load, never touched by workspace poison,
// never reset), gen[k] advances only after all arrivals of the round.
// New here (R5 post-mortem: ~80us/barrier was CONTENTION, not protocol):
//   * every counter in its own 128B slot (R5 had arrive/gen false-shared)
//   * 8-leaf arrival tree: 32 RMWs/line across 8 lines, then 8 root RMWs
//   * poll backoff: 8 fast polls (s_sleep(2)) then s_sleep(64) ~1.7us period
//   * s_waitcnt vmcnt(0) between gen-read and arrival (closes read-after-
//     release race; also compiler reorder fence via "memory")
struct alignas(128) BarSlot { int v; int pad_[31]; };
__device__ BarSlot g_leaf[2][8];
__device__ BarSlot g_root[2];
__device__ BarSlot g_gen[2];

__device__ __forceinline__ void gridbar(int k, int bid) {
    __syncthreads();   // drains this block's MALL-bound data stores (vmcnt 0)
    if (threadIdx.x == 0) {
        int g = __hip_atomic_load(&g_gen[k].v, __ATOMIC_RELAXED, AGT);
        asm volatile("s_waitcnt vmcnt(0)" ::: "memory");  // g observed BEFORE we arrive
        int a = __hip_atomic_fetch_add(&g_leaf[k][bid >> 5].v, 1, __ATOMIC_RELAXED, AGT);
        if ((a & 31) == 31) {                       // last of this leaf's 32 blocks
            int r = __hip_atomic_fetch_add(&g_root[k].v, 1, __ATOMIC_RELAXED, AGT);
            if ((r & 7) == 7) {                     // last leaf -> release
                __hip_atomic_fetch_add(&g_gen[k].v, 1, __ATOMIC_RELAXED, AGT);
            }
        }
        int spins = 0;
        while (__hip_atomic_load(&g_gen[k].v, __ATOMIC_RELAXED, AGT) == g) {
            if (spins < 8) __builtin_amdgcn_s_sleep(2);   // fast path: barrier nearly done
            else           __builtin_amdgcn_s_sleep(64);  // ~1.7us, kills poll storm
            if (++spins > 100000) break;                  // fail loud, not hang
        }
    }
    __syncthreads();
}

// ---------------- Fused persistent kernel: proj -> bar -> weights -> bar -> final
__global__ __launch_bounds__(FUSED_BLOCK, 4)
void fused_kernel(const fv4* __restrict__ x4, const fv4* __restrict__ W4,
                  const int* __restrict__ row, const int* __restrict__ col,
                  const int* __restrict__ fri,
                  float* __restrict__ sl, float* __restrict__ sr,
                  unsigned short* __restrict__ wbf, float* __restrict__ out,
                  int n, int e) {
    const int gsz = FUSED_GRID * FUSED_BLOCK;              // 262144, mult of 32
    const int bid = blockIdx.x;
    const int gid = bid * FUSED_BLOCK + threadIdx.x;
    const int sub = gid & 31;                              // invariant under stride

    // ---- Phase A: per-node projections, 32 lanes/node ----
    // x/W read-only inputs: plain cached loads. sl/sr stores MALL-direct.
    const fv4 wl = W4[sub];        // W[0, 0:128]   = Wl
    const fv4 wr = W4[32 + sub];   // W[0, 128:256] = Wr
    const long long n32 = (long long)n * 32;
    for (long long t = gid; t < n32; t += gsz) {
        fv4 v = x4[t];             // t = node*32 + sub exactly; fully coalesced
        float pl = v.x * wl.x + v.y * wl.y + v.z * wl.z + v.w * wl.w;
        float pr = v.x * wr.x + v.y * wr.y + v.z * wr.z + v.w * wr.w;
#pragma unroll
        for (int off = 16; off; off >>= 1) {   // stays within 32-lane half
            pl += __shfl_xor(pl, off);
            pr += __shfl_xor(pr, off);
        }
        if (sub == 0) {
            int node = (int)(t >> 5);
            ast_f32(&sl[node], pl);
            ast_f32(&sr[node], pr);
        }
    }
    gridbar(0, bid);

    // ---- Phase B: edge weights -> bf16 table ----
    // sl/sr gathers CACHED (800KB, L2-resident). wbf store MALL-direct.
    const int tv4 = (e + 3) >> 2;
    const int i0 = gid;
    const int i1 = gid + gsz;       // tv4=400000 < 2*gsz -> exactly <=2 quads/thread
    fv4 s0, s1;                     // f32 own-weights, live across the barrier

    if (i0 < tv4) {
        int base = i0 * 4;
        if (base + 3 < e) {
            iv4 r = __builtin_nontemporal_load(((const iv4*)row) + i0);
            iv4 c = __builtin_nontemporal_load(((const iv4*)col) + i0);
            s0.x = sigmoidf_(sl[r.x] + sr[c.x]);
            s0.y = sigmoidf_(sl[r.y] + sr[c.y]);
            s0.z = sigmoidf_(sl[r.z] + sr[c.z]);
            s0.w = sigmoidf_(sl[r.w] + sr[c.w]);
            unsigned long long pk =  (unsigned long long)f2bf(s0.x)
                                  | ((unsigned long long)f2bf(s0.y) << 16)
                                  | ((unsigned long long)f2bf(s0.z) << 32)
                                  | ((unsigned long long)f2bf(s0.w) << 48);
            ast_u64(((unsigned long long*)wbf) + i0, pk);
        } else {                     // unreachable at e%4==0; kept for generality
            for (int j = base; j < e; ++j)
                wbf[j] = f2bf(sigmoidf_(sl[row[j]] + sr[col[j]]));
        }
    }
    if (i1 < tv4) {
        int base = i1 * 4;
        if (base + 3 < e) {
            iv4 r = __builtin_nontemporal_load(((const iv4*)row) + i1);
            iv4 c = __builtin_nontemporal_load(((const iv4*)col) + i1);
            s1.x = sigmoidf_(sl[r.x] + sr[c.x]);
            s1.y = sigmoidf_(sl[r.y] + sr[c.y]);
            s1.z = sigmoidf_(sl[r.z] + sr[c.z]);
            s1.w = sigmoidf_(sl[r.w] + sr[c.w]);
            unsigned long long pk =  (unsigned long long)f2bf(s1.x)
                                  | ((unsigned long long)f2bf(s1.y) << 16)
                                  | ((unsigned long long)f2bf(s1.z) << 32)
                                  | ((unsigned long long)f2bf(s1.w) << 48);
            ast_u64(((unsigned long long*)wbf) + i1, pk);
        } else {
            for (int j = base; j < e; ++j)
                wbf[j] = f2bf(sigmoidf_(sl[row[j]] + sr[col[j]]));
        }
    }
    // safety net if e ever grows past 2 quads/thread (doesn't run at E=1.6M)
    for (int i = gid + 2 * gsz; i < tv4; i += gsz) {
        int base = i * 4;
        if (base + 3 < e) {
            iv4 r = __builtin_nontemporal_load(((const iv4*)row) + i);
            iv4 c = __builtin_nontemporal_load(((const iv4*)col) + i);
            unsigned long long pk =
                  (unsigned long long)f2bf(sigmoidf_(sl[r.x] + sr[c.x]))
                | ((unsigned long long)f2bf(sigmoidf_(sl[r.y] + sr[c.y])) << 16)
                | ((unsigned long long)f2bf(sigmoidf_(sl[r.z] + sr[c.z])) << 32)
                | ((unsigned long long)f2bf(sigmoidf_(sl[r.w] + sr[c.w])) << 48);
            ast_u64(((unsigned long long*)wbf) + i, pk);
        } else {
            for (int j = base; j < e; ++j)
                wbf[j] = f2bf(sigmoidf_(sl[row[j]] + sr[col[j]]));
        }
    }
    gridbar(1, bid);

    // ---- Phase C: gathered product (own weight from registers) ----
    // wbf gathers CACHED (3.2MB table, L2/MALL-resident).
    if (i0 < tv4) {
        int base = i0 * 4;
        if (base + 3 < e) {          // same predicate as phase B -> s0 is valid
            iv4 f = __builtin_nontemporal_load(((const iv4*)fri) + i0);
            float b0 = bf2f(wbf[f.x]);   // 4 independent random gathers in flight
            float b1 = bf2f(wbf[f.y]);
            float b2 = bf2f(wbf[f.z]);
            float b3 = bf2f(wbf[f.w]);
            fv4 o;
            o.x = s0.x * b0; o.y = s0.y * b1; o.z = s0.z * b2; o.w = s0.w * b3;
            __builtin_nontemporal_store(o, ((fv4*)out) + i0);
        } else {
            for (int j = base; j < e; ++j)
                out[j] = bf2f(wbf[j]) * bf2f(wbf[fri[j]]);
        }
    }
    if (i1 < tv4) {
        int base = i1 * 4;
        if (base + 3 < e) {
            iv4 f = __builtin_nontemporal_load(((const iv4*)fri) + i1);
            float b0 = bf2f(wbf[f.x]);
            float b1 = bf2f(wbf[f.y]);
            float b2 = bf2f(wbf[f.z]);
            float b3 = bf2f(wbf[f.w]);
            fv4 o;
            o.x = s1.x * b0; o.y = s1.y * b1; o.z = s1.z * b2; o.w = s1.w * b3;
            __builtin_nontemporal_store(o, ((fv4*)out) + i1);
        } else {
            for (int j = base; j < e; ++j)
                out[j] = bf2f(wbf[j]) * bf2f(wbf[fri[j]]);
        }
    }
    for (int i = gid + 2 * gsz; i < tv4; i += gsz) {
        int base = i * 4;
        if (base + 3 < e) {
            iv4 f = __builtin_nontemporal_load(((const iv4*)fri) + i);
            sv4 h = ((const sv4*)wbf)[i];
            fv4 o;
            o.x = bf2f(h.x) * bf2f(wbf[f.x]);
            o.y = bf2f(h.y) * bf2f(wbf[f.y]);
            o.z = bf2f(h.z) * bf2f(wbf[f.z]);
            o.w = bf2f(h.w) * bf2f(wbf[f.w]);
            __builtin_nontemporal_store(o, ((fv4*)out) + i);
        } else {
            for (int j = base; j < e; ++j)
                out[j] = bf2f(wbf[j]) * bf2f(wbf[fri[j]]);
        }
    }
}

// ---------------- K1: per-node projections (fallback path) -----------------
__global__ void proj_kernel(const fv4* __restrict__ x4, const fv4* __restrict__ W4,
                            float* __restrict__ sl, float* __restrict__ sr, int n) {
    int gid  = blockIdx.x * blockDim.x + threadIdx.x;
    int node = gid >> 5;
    int sub  = gid & 31;
    if (node >= n) return;
    fv4 v  = x4[(size_t)node * 32 + sub];
    fv4 wl = W4[sub];
    fv4 wr = W4[32 + sub];
    float pl = v.x * wl.x + v.y * wl.y + v.z * wl.z + v.w * wl.w;
    float pr = v.x * wr.x + v.y * wr.y + v.z * wr.z + v.w * wr.w;
#pragma unroll
    for (int off = 16; off; off >>= 1) {
        pl += __shfl_xor(pl, off);
        pr += __shfl_xor(pr, off);
    }
    if (sub == 0) { sl[node] = pl; sr[node] = pr; }
}

// ---------------- K2: edge weights -> bf16 (fallback path) -----------------
__global__ __launch_bounds__(256)
void weights_bf_kernel(const int* __restrict__ row, const int* __restrict__ col,
                       const float* __restrict__ sl, const float* __restrict__ sr,
                       unsigned short* __restrict__ wbf, int e) {
    int i = blockIdx.x * blockDim.x + threadIdx.x;
    int base = i * 4;
    if (base + 3 < e) {
        iv4 r = __builtin_nontemporal_load(((const iv4*)row) + i);
        iv4 c = __builtin_nontemporal_load(((const iv4*)col) + i);
        sv4 h;
        h.x = f2bf(sigmoidf_(sl[r.x] + sr[c.x]));
        h.y = f2bf(sigmoidf_(sl[r.y] + sr[c.y]));
        h.z = f2bf(sigmoidf_(sl[r.z] + sr[c.z]));
        h.w = f2bf(sigmoidf_(sl[r.w] + sr[c.w]));
        ((sv4*)wbf)[i] = h;
    } else if (base < e) {
        for (int j = base; j < e; ++j)
            wbf[j] = f2bf(sigmoidf_(sl[row[j]] + sr[col[j]]));
    }
}

// ---------------- K3: gathered product (fallback path) ---------------------
__global__ __launch_bounds__(256)
void final4_kernel(const unsigned short* __restrict__ wbf,
                   const int* __restrict__ fri, float* __restrict__ out, int e) {
    int i = blockIdx.x * blockDim.x + threadIdx.x;
    int base = i * 4;
    if (base + 3 < e) {
        iv4 f = __builtin_nontemporal_load(((const iv4*)fri) + i);
        sv4 h = ((const sv4*)wbf)[i];
        float b0 = bf2f(wbf[f.x]);
        float b1 = bf2f(wbf[f.y]);
        float b2 = bf2f(wbf[f.z]);
        float b3 = bf2f(wbf[f.w]);
        fv4 o;
        o.x = bf2f(h.x) * b0;
        o.y = bf2f(h.y) * b1;
        o.z = bf2f(h.z) * b2;
        o.w = bf2f(h.w) * b3;
        __builtin_nontemporal_store(o, ((fv4*)out) + i);
    } else if (base < e) {
        for (int j = base; j < e; ++j)
            out[j] = bf2f(wbf[j]) * bf2f(wbf[fri[j]]);
    }
}

// ---------------- Fallbacks ------------------------------------------------
__global__ void recompute_kernel(const int* __restrict__ row, const int* __restrict__ col,
                                 const int* __restrict__ fri,
                                 const float* __restrict__ sl, const float* __restrict__ sr,
                                 float* __restrict__ out, int e) {
    int i = blockIdx.x * blockDim.x + threadIdx.x;
    if (i >= e) return;
    int f = fri[i];
    float wa = sigmoidf_(sl[row[i]] + sr[col[i]]);
    float wb = sigmoidf_(sl[row[f]] + sr[col[f]]);
    out[i] = wa * wb;
}

__global__ void naive_kernel(const float* __restrict__ x, const float* __restrict__ W,
                             const int* __restrict__ row, const int* __restrict__ col,
                             const int* __restrict__ fri, float* __restrict__ out, int e) {
    int gid  = blockIdx.x * blockDim.x + threadIdx.x;
    int edge = gid >> 6;
    int lane = gid & 63;
    if (edge >= e) return;
    int f = fri[edge];
    const float2* X = (const float2*)x;
    float2 wl = ((const float2*)W)[lane];
    float2 wr = ((const float2*)W)[64 + lane];
    float2 a1 = X[(size_t)row[edge] * 64 + lane];
    float2 b1 = X[(size_t)col[edge] * 64 + lane];
    float2 a2 = X[(size_t)row[f] * 64 + lane];
    float2 b2 = X[(size_t)col[f] * 64 + lane];
    float p1 = a1.x * wl.x + a1.y * wl.y + b1.x * wr.x + b1.y * wr.y;
    float p2 = a2.x * wl.x + a2.y * wl.y + b2.x * wr.x + b2.y * wr.y;
#pragma unroll
    for (int off = 32; off; off >>= 1) {
        p1 += __shfl_xor(p1, off);
        p2 += __shfl_xor(p2, off);
    }
    if (lane == 0) out[edge] = sigmoidf_(p1) * sigmoidf_(p2);
}

extern "C" void kernel_launch(void* const* d_in, const int* in_sizes, int n_in,
                              void* d_out, int out_size, void* d_ws, size_t ws_size,
                              hipStream_t stream) {
    const float* x   = (const float*)d_in[0];
    const int*   ei  = (const int*)d_in[1];
    const int*   fri = (const int*)d_in[2];
    const float* W   = (const float*)d_in[3];
    float* out = (float*)d_out;

    const int n = in_sizes[0] / CDIM;   // 100000 nodes
    const int e = in_sizes[2];          // 1600000 edges
    const int* row = ei;
    const int* col = ei + e;

    const size_t need_s  = (size_t)2 * n * sizeof(float);
    const size_t need_bf = need_s + (size_t)e * sizeof(unsigned short);

    float* sl = (float*)d_ws;
    float* sr = sl + n;

    const int BS = 256;
    const int tv4 = (e + 3) / 4;
    const long long proj_threads = (long long)n * 32;
    const int proj_grid = (int)((proj_threads + BS - 1) / BS);

    if (ws_size >= need_bf) {
        unsigned short* wbf = (unsigned short*)(sr + n);

        const fv4* x4p = (const fv4*)x;
        const fv4* W4p = (const fv4*)W;
        const int* rowp = row;
        const int* colp = col;
        const int* frip = fri;
        float* slp = sl;
        float* srp = sr;
        unsigned short* wbfp = wbf;
        float* outp = out;
        int nn = n, ee = e;
        void* kargs[] = {&x4p, &W4p, &rowp, &colp, &frip,
                         &slp, &srp, &wbfp, &outp, &nn, &ee};
        hipError_t err = hipLaunchCooperativeKernel(
            (const void*)fused_kernel, dim3(FUSED_GRID), dim3(FUSED_BLOCK),
            kargs, 0, stream);
        if (err != hipSuccess) {
            // proven 3-kernel fallback
            proj_kernel<<<proj_grid, BS, 0, stream>>>((const fv4*)x, (const fv4*)W, sl, sr, n);
            weights_bf_kernel<<<(tv4 + BS - 1) / BS, BS, 0, stream>>>(row, col, sl, sr, wbf, e);
            final4_kernel<<<(tv4 + BS - 1) / BS, BS, 0, stream>>>(wbf, fri, out, e);
        }
    } else if (ws_size >= need_s) {
        proj_kernel<<<proj_grid, BS, 0, stream>>>((const fv4*)x, (const fv4*)W, sl, sr, n);
        recompute_kernel<<<(e + BS - 1) / BS, BS, 0, stream>>>(row, col, fri, sl, sr, out, e);
    } else {
        long long t = (long long)e * 64;
        naive_kernel<<<(int)((t + BS - 1) / BS), BS, 0, stream>>>(x, W, row, col, fri, out, e);
    }
}

// Round 7
// 66.722 us; speedup vs baseline: 3.6661x; 1.0800x over previous
//
#include <hip/hip_runtime.h>

#define CDIM 128          // feature dim C
#define FUSED_GRID 512    // 2 blocks/CU on 256 CUs -> 32 waves/CU (coop launch verifies)
#define FUSED_BLOCK 1024

// Native clang vectors — required by __builtin_nontemporal_load/store
typedef int            iv4 __attribute__((ext_vector_type(4)));
typedef float          fv4 __attribute__((ext_vector_type(4)));
typedef unsigned short sv4 __attribute__((ext_vector_type(4)));

__device__ __forceinline__ float sigmoidf_(float t) {
    return 1.0f / (1.0f + __expf(-t));
}
__device__ __forceinline__ unsigned short f2bf(float x) {   // round-to-nearest-even
    unsigned u = __float_as_uint(x);
    u += 0x7fffu + ((u >> 16) & 1u);
    return (unsigned short)(u >> 16);
}
__device__ __forceinline__ float bf2f(unsigned short h) {
    return __uint_as_float(((unsigned)h) << 16);
}

// Agent-scope (MALL-coherent, cache-bypassing) STORE helpers. Only stores are
// MALL-direct: readers use cached loads (L2 starts invalidated each dispatch,
// and sl/sr/wbf are never read before their producing barrier, so no XCD L2
// can hold a stale line at first read).                       [proven R4-R6]
#define AGT __HIP_MEMORY_SCOPE_AGENT
__device__ __forceinline__ void ast_f32(float* p, float x) {
    __hip_atomic_store((unsigned*)(void*)p, __float_as_uint(x), __ATOMIC_RELAXED, AGT);
}
__device__ __forceinline__ void ast_u64(unsigned long long* p, unsigned long long v) {
    __hip_atomic_store(p, v, __ATOMIC_RELAXED, AGT);
}

// ---------------- monotonic generation grid barrier, contention-engineered --
// Logic proven R4-R6 (monotonic counters in __device__ globals: zero at .so
// load, never touched by workspace poison, never reset; gen[k] advances only
// after all arrivals of the round). R6 proved the contention engineering
// (128B slots, leaf tree, sleep backoff) took barriers from ~80us to ~us.
// R7 rescale: 512 blocks -> 16 leaves x 32 blocks; sleep quantum 32 (~0.85us)
// since the co-resident second block per CU now hides leader sleep.
struct alignas(128) BarSlot { int v; int pad_[31]; };
__device__ BarSlot g_leaf[2][16];
__device__ BarSlot g_root[2];
__device__ BarSlot g_gen[2];

__device__ __forceinline__ void gridbar(int k, int bid) {
    __syncthreads();   // drains this block's MALL-bound data stores (vmcnt 0)
    if (threadIdx.x == 0) {
        int g = __hip_atomic_load(&g_gen[k].v, __ATOMIC_RELAXED, AGT);
        asm volatile("s_waitcnt vmcnt(0)" ::: "memory");  // g observed BEFORE we arrive
        int a = __hip_atomic_fetch_add(&g_leaf[k][bid >> 5].v, 1, __ATOMIC_RELAXED, AGT);
        if ((a & 31) == 31) {                       // last of this leaf's 32 blocks
            int r = __hip_atomic_fetch_add(&g_root[k].v, 1, __ATOMIC_RELAXED, AGT);
            if ((r & 15) == 15) {                   // last of 16 leaves -> release
                __hip_atomic_fetch_add(&g_gen[k].v, 1, __ATOMIC_RELAXED, AGT);
            }
        }
        int spins = 0;
        while (__hip_atomic_load(&g_gen[k].v, __ATOMIC_RELAXED, AGT) == g) {
            if (spins < 8) __builtin_amdgcn_s_sleep(2);   // fast path: barrier nearly done
            else           __builtin_amdgcn_s_sleep(32);  // ~0.85us, kills poll storm
            if (++spins > 200000) break;                  // fail loud, not hang
        }
    }
    __syncthreads();
}

// ---------------- Fused persistent kernel: proj -> bar -> weights -> bar -> final
__global__ __launch_bounds__(FUSED_BLOCK, 2)
void fused_kernel(const fv4* __restrict__ x4, const fv4* __restrict__ W4,
                  const int* __restrict__ row, const int* __restrict__ col,
                  const int* __restrict__ fri,
                  float* __restrict__ sl, float* __restrict__ sr,
                  unsigned short* __restrict__ wbf, float* __restrict__ out,
                  int n, int e) {
    const int gsz = FUSED_GRID * FUSED_BLOCK;              // 524288, mult of 32
    const int bid = blockIdx.x;
    const int gid = bid * FUSED_BLOCK + threadIdx.x;
    const int sub = gid & 31;                              // invariant under stride

    // ---- Phase A: per-node projections, 32 lanes/node ----
    // x/W read-only inputs: plain cached loads. sl/sr stores MALL-direct.
    const fv4 wl = W4[sub];        // W[0, 0:128]   = Wl
    const fv4 wr = W4[32 + sub];   // W[0, 128:256] = Wr
    const long long n32 = (long long)n * 32;
    for (long long t = gid; t < n32; t += gsz) {
        fv4 v = x4[t];             // t = node*32 + sub exactly; fully coalesced
        float pl = v.x * wl.x + v.y * wl.y + v.z * wl.z + v.w * wl.w;
        float pr = v.x * wr.x + v.y * wr.y + v.z * wr.z + v.w * wr.w;
#pragma unroll
        for (int off = 16; off; off >>= 1) {   // stays within 32-lane half
            pl += __shfl_xor(pl, off);
            pr += __shfl_xor(pr, off);
        }
        if (sub == 0) {
            int node = (int)(t >> 5);
            ast_f32(&sl[node], pl);
            ast_f32(&sr[node], pr);
        }
    }
    gridbar(0, bid);

    // ---- Phase B: edge weights -> bf16 table ----
    // sl/sr gathers CACHED (800KB, L2-resident). wbf store MALL-direct.
    const int tv4 = (e + 3) >> 2;
    const int i0 = gid;
    const int i1 = gid + gsz;       // tv4=400000 < gsz -> i1 path predicates off
    fv4 s0, s1;                     // f32 own-weights, live across the barrier

    if (i0 < tv4) {
        int base = i0 * 4;
        if (base + 3 < e) {
            iv4 r = __builtin_nontemporal_load(((const iv4*)row) + i0);
            iv4 c = __builtin_nontemporal_load(((const iv4*)col) + i0);
            s0.x = sigmoidf_(sl[r.x] + sr[c.x]);
            s0.y = sigmoidf_(sl[r.y] + sr[c.y]);
            s0.z = sigmoidf_(sl[r.z] + sr[c.z]);
            s0.w = sigmoidf_(sl[r.w] + sr[c.w]);
            unsigned long long pk =  (unsigned long long)f2bf(s0.x)
                                  | ((unsigned long long)f2bf(s0.y) << 16)
                                  | ((unsigned long long)f2bf(s0.z) << 32)
                                  | ((unsigned long long)f2bf(s0.w) << 48);
            ast_u64(((unsigned long long*)wbf) + i0, pk);
        } else {                     // unreachable at e%4==0; kept for generality
            for (int j = base; j < e; ++j)
                wbf[j] = f2bf(sigmoidf_(sl[row[j]] + sr[col[j]]));
        }
    }
    if (i1 < tv4) {
        int base = i1 * 4;
        if (base + 3 < e) {
            iv4 r = __builtin_nontemporal_load(((const iv4*)row) + i1);
            iv4 c = __builtin_nontemporal_load(((const iv4*)col) + i1);
            s1.x = sigmoidf_(sl[r.x] + sr[c.x]);
            s1.y = sigmoidf_(sl[r.y] + sr[c.y]);
            s1.z = sigmoidf_(sl[r.z] + sr[c.z]);
            s1.w = sigmoidf_(sl[r.w] + sr[c.w]);
            unsigned long long pk =  (unsigned long long)f2bf(s1.x)
                                  | ((unsigned long long)f2bf(s1.y) << 16)
                                  | ((unsigned long long)f2bf(s1.z) << 32)
                                  | ((unsigned long long)f2bf(s1.w) << 48);
            ast_u64(((unsigned long long*)wbf) + i1, pk);
        } else {
            for (int j = base; j < e; ++j)
                wbf[j] = f2bf(sigmoidf_(sl[row[j]] + sr[col[j]]));
        }
    }
    // safety net if e ever grows past 2 quads/thread (doesn't run at E=1.6M)
    for (int i = gid + 2 * gsz; i < tv4; i += gsz) {
        int base = i * 4;
        if (base + 3 < e) {
            iv4 r = __builtin_nontemporal_load(((const iv4*)row) + i);
            iv4 c = __builtin_nontemporal_load(((const iv4*)col) + i);
            unsigned long long pk =
                  (unsigned long long)f2bf(sigmoidf_(sl[r.x] + sr[c.x]))
                | ((unsigned long long)f2bf(sigmoidf_(sl[r.y] + sr[c.y])) << 16)
                | ((unsigned long long)f2bf(sigmoidf_(sl[r.z] + sr[c.z])) << 32)
                | ((unsigned long long)f2bf(sigmoidf_(sl[r.w] + sr[c.w])) << 48);
            ast_u64(((unsigned long long*)wbf) + i, pk);
        } else {
            for (int j = base; j < e; ++j)
                wbf[j] = f2bf(sigmoidf_(sl[row[j]] + sr[col[j]]));
        }
    }
    gridbar(1, bid);

    // ---- Phase C: gathered product (own weight from registers) ----
    // wbf gathers CACHED (3.2MB table, L2/MALL-resident).
    if (i0 < tv4) {
        int base = i0 * 4;
        if (base + 3 < e) {          // same predicate as phase B -> s0 is valid
            iv4 f = __builtin_nontemporal_load(((const iv4*)fri) + i0);
            float b0 = bf2f(wbf[f.x]);   // 4 independent random gathers in flight
            float b1 = bf2f(wbf[f.y]);
            float b2 = bf2f(wbf[f.z]);
            float b3 = bf2f(wbf[f.w]);
            fv4 o;
            o.x = s0.x * b0; o.y = s0.y * b1; o.z = s0.z * b2; o.w = s0.w * b3;
            __builtin_nontemporal_store(o, ((fv4*)out) + i0);
        } else {
            for (int j = base; j < e; ++j)
                out[j] = bf2f(wbf[j]) * bf2f(wbf[fri[j]]);
        }
    }
    if (i1 < tv4) {
        int base = i1 * 4;
        if (base + 3 < e) {
            iv4 f = __builtin_nontemporal_load(((const iv4*)fri) + i1);
            float b0 = bf2f(wbf[f.x]);
            float b1 = bf2f(wbf[f.y]);
            float b2 = bf2f(wbf[f.z]);
            float b3 = bf2f(wbf[f.w]);
            fv4 o;
            o.x = s1.x * b0; o.y = s1.y * b1; o.z = s1.z * b2; o.w = s1.w * b3;
            __builtin_nontemporal_store(o, ((fv4*)out) + i1);
        } else {
            for (int j = base; j < e; ++j)
                out[j] = bf2f(wbf[j]) * bf2f(wbf[fri[j]]);
        }
    }
    for (int i = gid + 2 * gsz; i < tv4; i += gsz) {
        int base = i * 4;
        if (base + 3 < e) {
            iv4 f = __builtin_nontemporal_load(((const iv4*)fri) + i);
            sv4 h = ((const sv4*)wbf)[i];
            fv4 o;
            o.x = bf2f(h.x) * bf2f(wbf[f.x]);
            o.y = bf2f(h.y) * bf2f(wbf[f.y]);
            o.z = bf2f(h.z) * bf2f(wbf[f.z]);
            o.w = bf2f(h.w) * bf2f(wbf[f.w]);
            __builtin_nontemporal_store(o, ((fv4*)out) + i);
        } else {
            for (int j = base; j < e; ++j)
                out[j] = bf2f(wbf[j]) * bf2f(wbf[fri[j]]);
        }
    }
}

// ---------------- K1: per-node projections (fallback path) -----------------
__global__ void proj_kernel(const fv4* __restrict__ x4, const fv4* __restrict__ W4,
                            float* __restrict__ sl, float* __restrict__ sr, int n) {
    int gid  = blockIdx.x * blockDim.x + threadIdx.x;
    int node = gid >> 5;
    int sub  = gid & 31;
    if (node >= n) return;
    fv4 v  = x4[(size_t)node * 32 + sub];
    fv4 wl = W4[sub];
    fv4 wr = W4[32 + sub];
    float pl = v.x * wl.x + v.y * wl.y + v.z * wl.z + v.w * wl.w;
    float pr = v.x * wr.x + v.y * wr.y + v.z * wr.z + v.w * wr.w;
#pragma unroll
    for (int off = 16; off; off >>= 1) {
        pl += __shfl_xor(pl, off);
        pr += __shfl_xor(pr, off);
    }
    if (sub == 0) { sl[node] = pl; sr[node] = pr; }
}

// ---------------- K2: edge weights -> bf16 (fallback path) -----------------
__global__ __launch_bounds__(256)
void weights_bf_kernel(const int* __restrict__ row, const int* __restrict__ col,
                       const float* __restrict__ sl, const float* __restrict__ sr,
                       unsigned short* __restrict__ wbf, int e) {
    int i = blockIdx.x * blockDim.x + threadIdx.x;
    int base = i * 4;
    if (base + 3 < e) {
        iv4 r = __builtin_nontemporal_load(((const iv4*)row) + i);
        iv4 c = __builtin_nontemporal_load(((const iv4*)col) + i);
        sv4 h;
        h.x = f2bf(sigmoidf_(sl[r.x] + sr[c.x]));
        h.y = f2bf(sigmoidf_(sl[r.y] + sr[c.y]));
        h.z = f2bf(sigmoidf_(sl[r.z] + sr[c.z]));
        h.w = f2bf(sigmoidf_(sl[r.w] + sr[c.w]));
        ((sv4*)wbf)[i] = h;
    } else if (base < e) {
        for (int j = base; j < e; ++j)
            wbf[j] = f2bf(sigmoidf_(sl[row[j]] + sr[col[j]]));
    }
}

// ---------------- K3: gathered product (fallback path) ---------------------
__global__ __launch_bounds__(256)
void final4_kernel(const unsigned short* __restrict__ wbf,
                   const int* __restrict__ fri, float* __restrict__ out, int e) {
    int i = blockIdx.x * blockDim.x + threadIdx.x;
    int base = i * 4;
    if (base + 3 < e) {
        iv4 f = __builtin_nontemporal_load(((const iv4*)fri) + i);
        sv4 h = ((const sv4*)wbf)[i];
        float b0 = bf2f(wbf[f.x]);
        float b1 = bf2f(wbf[f.y]);
        float b2 = bf2f(wbf[f.z]);
        float b3 = bf2f(wbf[f.w]);
        fv4 o;
        o.x = bf2f(h.x) * b0;
        o.y = bf2f(h.y) * b1;
        o.z = bf2f(h.z) * b2;
        o.w = bf2f(h.w) * b3;
        __builtin_nontemporal_store(o, ((fv4*)out) + i);
    } else if (base < e) {
        for (int j = base; j < e; ++j)
            out[j] = bf2f(wbf[j]) * bf2f(wbf[fri[j]]);
    }
}

// ---------------- Fallbacks ------------------------------------------------
__global__ void recompute_kernel(const int* __restrict__ row, const int* __restrict__ col,
                                 const int* __restrict__ fri,
                                 const float* __restrict__ sl, const float* __restrict__ sr,
                                 float* __restrict__ out, int e) {
    int i = blockIdx.x * blockDim.x + threadIdx.x;
    if (i >= e) return;
    int f = fri[i];
    float wa = sigmoidf_(sl[row[i]] + sr[col[i]]);
    float wb = sigmoidf_(sl[row[f]] + sr[col[f]]);
    out[i] = wa * wb;
}

__global__ void naive_kernel(const float* __restrict__ x, const float* __restrict__ W,
                             const int* __restrict__ row, const int* __restrict__ col,
                             const int* __restrict__ fri, float* __restrict__ out, int e) {
    int gid  = blockIdx.x * blockDim.x + threadIdx.x;
    int edge = gid >> 6;
    int lane = gid & 63;
    if (edge >= e) return;
    int f = fri[edge];
    const float2* X = (const float2*)x;
    float2 wl = ((const float2*)W)[lane];
    float2 wr = ((const float2*)W)[64 + lane];
    float2 a1 = X[(size_t)row[edge] * 64 + lane];
    float2 b1 = X[(size_t)col[edge] * 64 + lane];
    float2 a2 = X[(size_t)row[f] * 64 + lane];
    float2 b2 = X[(size_t)col[f] * 64 + lane];
    float p1 = a1.x * wl.x + a1.y * wl.y + b1.x * wr.x + b1.y * wr.y;
    float p2 = a2.x * wl.x + a2.y * wl.y + b2.x * wr.x + b2.y * wr.y;
#pragma unroll
    for (int off = 32; off; off >>= 1) {
        p1 += __shfl_xor(p1, off);
        p2 += __shfl_xor(p2, off);
    }
    if (lane == 0) out[edge] = sigmoidf_(p1) * sigmoidf_(p2);
}

extern "C" void kernel_launch(void* const* d_in, const int* in_sizes, int n_in,
                              void* d_out, int out_size, void* d_ws, size_t ws_size,
                              hipStream_t stream) {
    const float* x   = (const float*)d_in[0];
    const int*   ei  = (const int*)d_in[1];
    const int*   fri = (const int*)d_in[2];
    const float* W   = (const float*)d_in[3];
    float* out = (float*)d_out;

    const int n = in_sizes[0] / CDIM;   // 100000 nodes
    const int e = in_sizes[2];          // 1600000 edges
    const int* row = ei;
    const int* col = ei + e;

    const size_t need_s  = (size_t)2 * n * sizeof(float);
    const size_t need_bf = need_s + (size_t)e * sizeof(unsigned short);

    float* sl = (float*)d_ws;
    float* sr = sl + n;

    const int BS = 256;
    const int tv4 = (e + 3) / 4;
    const long long proj_threads = (long long)n * 32;
    const int proj_grid = (int)((proj_threads + BS - 1) / BS);

    if (ws_size >= need_bf) {
        unsigned short* wbf = (unsigned short*)(sr + n);

        const fv4* x4p = (const fv4*)x;
        const fv4* W4p = (const fv4*)W;
        const int* rowp = row;
        const int* colp = col;
        const int* frip = fri;
        float* slp = sl;
        float* srp = sr;
        unsigned short* wbfp = wbf;
        float* outp = out;
        int nn = n, ee = e;
        void* kargs[] = {&x4p, &W4p, &rowp, &colp, &frip,
                         &slp, &srp, &wbfp, &outp, &nn, &ee};
        hipError_t err = hipLaunchCooperativeKernel(
            (const void*)fused_kernel, dim3(FUSED_GRID), dim3(FUSED_BLOCK),
            kargs, 0, stream);
        if (err != hipSuccess) {
            // proven 3-kernel fallback
            proj_kernel<<<proj_grid, BS, 0, stream>>>((const fv4*)x, (const fv4*)W, sl, sr, n);
            weights_bf_kernel<<<(tv4 + BS - 1) / BS, BS, 0, stream>>>(row, col, sl, sr, wbf, e);
            final4_kernel<<<(tv4 + BS - 1) / BS, BS, 0, stream>>>(wbf, fri, out, e);
        }
    } else if (ws_size >= need_s) {
        proj_kernel<<<proj_grid, BS, 0, stream>>>((const fv4*)x, (const fv4*)W, sl, sr, n);
        recompute_kernel<<<(e + BS - 1) / BS, BS, 0, stream>>>(row, col, fri, sl, sr, out, e);
    } else {
        long long t = (long long)e * 64;
        naive_kernel<<<(int)((t + BS - 1) / BS), BS, 0, stream>>>(x, W, row, col, fri, out, e);
    }
}

// Round 8
// 47.937 us; speedup vs baseline: 5.1028x; 1.3919x over previous
//
#include <hip/hip_runtime.h>

#define CDIM 128          // feature dim C
#define FUSED_GRID 448    // 1.75 blocks/CU: any <=2/CU packing leaves none pending
#define FUSED_BLOCK 1024

// Native clang vectors — required by __builtin_nontemporal_load/store
typedef int            iv4 __attribute__((ext_vector_type(4)));
typedef float          fv4 __attribute__((ext_vector_type(4)));
typedef unsigned short sv4 __attribute__((ext_vector_type(4)));

__device__ __forceinline__ float sigmoidf_(float t) {
    return 1.0f / (1.0f + __expf(-t));
}
__device__ __forceinline__ unsigned short f2bf(float x) {   // round-to-nearest-even
    unsigned u = __float_as_uint(x);
    u += 0x7fffu + ((u >> 16) & 1u);
    return (unsigned short)(u >> 16);
}
__device__ __forceinline__ float bf2f(unsigned short h) {
    return __uint_as_float(((unsigned)h) << 16);
}

// Agent-scope (MALL-coherent, cache-bypassing) STORE helpers. Only stores are
// MALL-direct: readers use cached loads (L2 starts invalidated each dispatch,
// and sl/sr/wbf are never read before their producing barrier, so no XCD L2
// can hold a stale line at first read).                       [proven R4-R7]
#define AGT __HIP_MEMORY_SCOPE_AGENT
__device__ __forceinline__ void ast_f32(float* p, float x) {
    __hip_atomic_store((unsigned*)(void*)p, __float_as_uint(x), __ATOMIC_RELAXED, AGT);
}
__device__ __forceinline__ void ast_u64(unsigned long long* p, unsigned long long v) {
    __hip_atomic_store(p, v, __ATOMIC_RELAXED, AGT);
}

// ---------------- monotonic generation grid barrier, contention-engineered --
// Logic proven R4-R7 (monotonic counters in __device__ globals: zero at .so
// load, never touched by workspace poison, never reset; gen[k] advances only
// after all arrivals of the round). Contention engineering (128B slots, leaf
// tree, sleep backoff) proven R6: barriers ~us, not ~80us.
// R8: plain launch (not cooperative). Co-residency from capacity slack:
// 448 blocks at <=2/CU into 256 CUs -> all resident under greedy dispatch.
// 14 leaves x 32 blocks.
struct alignas(128) BarSlot { int v; int pad_[31]; };
__device__ BarSlot g_leaf[2][16];
__device__ BarSlot g_root[2];
__device__ BarSlot g_gen[2];

__device__ __forceinline__ void gridbar(int k, int bid) {
    __syncthreads();   // drains this block's MALL-bound data stores (vmcnt 0)
    if (threadIdx.x == 0) {
        int g = __hip_atomic_load(&g_gen[k].v, __ATOMIC_RELAXED, AGT);
        asm volatile("s_waitcnt vmcnt(0)" ::: "memory");  // g observed BEFORE we arrive
        int a = __hip_atomic_fetch_add(&g_leaf[k][bid >> 5].v, 1, __ATOMIC_RELAXED, AGT);
        if ((a & 31) == 31) {                       // last of this leaf's 32 blocks
            int r = __hip_atomic_fetch_add(&g_root[k].v, 1, __ATOMIC_RELAXED, AGT);
            if (((unsigned)r % (FUSED_GRID / 32)) == (FUSED_GRID / 32 - 1)) {
                __hip_atomic_fetch_add(&g_gen[k].v, 1, __ATOMIC_RELAXED, AGT);
            }
        }
        int spins = 0;
        while (__hip_atomic_load(&g_gen[k].v, __ATOMIC_RELAXED, AGT) == g) {
            if (spins < 8) __builtin_amdgcn_s_sleep(2);   // fast path: barrier nearly done
            else           __builtin_amdgcn_s_sleep(32);  // ~0.85us, kills poll storm
            if (++spins > 200000) break;                  // fail loud, not hang
        }
    }
    __syncthreads();
}

// ---------------- Fused persistent kernel: proj -> bar -> weights -> bar -> final
__global__ __launch_bounds__(FUSED_BLOCK, 2)
void fused_kernel(const fv4* __restrict__ x4, const fv4* __restrict__ W4,
                  const int* __restrict__ row, const int* __restrict__ col,
                  const int* __restrict__ fri,
                  float* __restrict__ sl, float* __restrict__ sr,
                  unsigned short* __restrict__ wbf, float* __restrict__ out,
                  int n, int e) {
    const int gsz = FUSED_GRID * FUSED_BLOCK;              // 458752, mult of 32
    const int bid = blockIdx.x;
    const int gid = bid * FUSED_BLOCK + threadIdx.x;
    const int sub = gid & 31;                              // invariant under stride

    // ---- Phase A: per-node projections, 32 lanes/node ----
    // x/W read-only inputs: plain cached loads. sl/sr stores MALL-direct.
    const fv4 wl = W4[sub];        // W[0, 0:128]   = Wl
    const fv4 wr = W4[32 + sub];   // W[0, 128:256] = Wr
    const long long n32 = (long long)n * 32;
    for (long long t = gid; t < n32; t += gsz) {
        fv4 v = x4[t];             // t = node*32 + sub exactly; fully coalesced
        float pl = v.x * wl.x + v.y * wl.y + v.z * wl.z + v.w * wl.w;
        float pr = v.x * wr.x + v.y * wr.y + v.z * wr.z + v.w * wr.w;
#pragma unroll
        for (int off = 16; off; off >>= 1) {   // stays within 32-lane half
            pl += __shfl_xor(pl, off);
            pr += __shfl_xor(pr, off);
        }
        if (sub == 0) {
            int node = (int)(t >> 5);
            ast_f32(&sl[node], pl);
            ast_f32(&sr[node], pr);
        }
    }
    gridbar(0, bid);

    // ---- Phase B: edge weights -> bf16 table ----
    // sl/sr gathers CACHED (800KB, L2-resident). wbf store MALL-direct.
    const int tv4 = (e + 3) >> 2;
    const int i0 = gid;
    const int i1 = gid + gsz;       // tv4=400000 < gsz -> i1 path predicates off
    fv4 s0, s1;                     // f32 own-weights, live across the barrier

    if (i0 < tv4) {
        int base = i0 * 4;
        if (base + 3 < e) {
            iv4 r = __builtin_nontemporal_load(((const iv4*)row) + i0);
            iv4 c = __builtin_nontemporal_load(((const iv4*)col) + i0);
            s0.x = sigmoidf_(sl[r.x] + sr[c.x]);
            s0.y = sigmoidf_(sl[r.y] + sr[c.y]);
            s0.z = sigmoidf_(sl[r.z] + sr[c.z]);
            s0.w = sigmoidf_(sl[r.w] + sr[c.w]);
            unsigned long long pk =  (unsigned long long)f2bf(s0.x)
                                  | ((unsigned long long)f2bf(s0.y) << 16)
                                  | ((unsigned long long)f2bf(s0.z) << 32)
                                  | ((unsigned long long)f2bf(s0.w) << 48);
            ast_u64(((unsigned long long*)wbf) + i0, pk);
        } else {                     // unreachable at e%4==0; kept for generality
            for (int j = base; j < e; ++j)
                wbf[j] = f2bf(sigmoidf_(sl[row[j]] + sr[col[j]]));
        }
    }
    if (i1 < tv4) {
        int base = i1 * 4;
        if (base + 3 < e) {
            iv4 r = __builtin_nontemporal_load(((const iv4*)row) + i1);
            iv4 c = __builtin_nontemporal_load(((const iv4*)col) + i1);
            s1.x = sigmoidf_(sl[r.x] + sr[c.x]);
            s1.y = sigmoidf_(sl[r.y] + sr[c.y]);
            s1.z = sigmoidf_(sl[r.z] + sr[c.z]);
            s1.w = sigmoidf_(sl[r.w] + sr[c.w]);
            unsigned long long pk =  (unsigned long long)f2bf(s1.x)
                                  | ((unsigned long long)f2bf(s1.y) << 16)
                                  | ((unsigned long long)f2bf(s1.z) << 32)
                                  | ((unsigned long long)f2bf(s1.w) << 48);
            ast_u64(((unsigned long long*)wbf) + i1, pk);
        } else {
            for (int j = base; j < e; ++j)
                wbf[j] = f2bf(sigmoidf_(sl[row[j]] + sr[col[j]]));
        }
    }
    // safety net if e ever grows past 2 quads/thread (doesn't run at E=1.6M)
    for (int i = gid + 2 * gsz; i < tv4; i += gsz) {
        int base = i * 4;
        if (base + 3 < e) {
            iv4 r = __builtin_nontemporal_load(((const iv4*)row) + i);
            iv4 c = __builtin_nontemporal_load(((const iv4*)col) + i);
            unsigned long long pk =
                  (unsigned long long)f2bf(sigmoidf_(sl[r.x] + sr[c.x]))
                | ((unsigned long long)f2bf(sigmoidf_(sl[r.y] + sr[c.y])) << 16)
                | ((unsigned long long)f2bf(sigmoidf_(sl[r.z] + sr[c.z])) << 32)
                | ((unsigned long long)f2bf(sigmoidf_(sl[r.w] + sr[c.w])) << 48);
            ast_u64(((unsigned long long*)wbf) + i, pk);
        } else {
            for (int j = base; j < e; ++j)
                wbf[j] = f2bf(sigmoidf_(sl[row[j]] + sr[col[j]]));
        }
    }
    gridbar(1, bid);

    // ---- Phase C: gathered product (own weight from registers) ----
    // wbf gathers CACHED (3.2MB table, L2/MALL-resident).
    if (i0 < tv4) {
        int base = i0 * 4;
        if (base + 3 < e) {          // same predicate as phase B -> s0 is valid
            iv4 f = __builtin_nontemporal_load(((const iv4*)fri) + i0);
            float b0 = bf2f(wbf[f.x]);   // 4 independent random gathers in flight
            float b1 = bf2f(wbf[f.y]);
            float b2 = bf2f(wbf[f.z]);
            float b3 = bf2f(wbf[f.w]);
            fv4 o;
            o.x = s0.x * b0; o.y = s0.y * b1; o.z = s0.z * b2; o.w = s0.w * b3;
            __builtin_nontemporal_store(o, ((fv4*)out) + i0);
        } else {
            for (int j = base; j < e; ++j)
                out[j] = bf2f(wbf[j]) * bf2f(wbf[fri[j]]);
        }
    }
    if (i1 < tv4) {
        int base = i1 * 4;
        if (base + 3 < e) {
            iv4 f = __builtin_nontemporal_load(((const iv4*)fri) + i1);
            float b0 = bf2f(wbf[f.x]);
            float b1 = bf2f(wbf[f.y]);
            float b2 = bf2f(wbf[f.z]);
            float b3 = bf2f(wbf[f.w]);
            fv4 o;
            o.x = s1.x * b0; o.y = s1.y * b1; o.z = s1.z * b2; o.w = s1.w * b3;
            __builtin_nontemporal_store(o, ((fv4*)out) + i1);
        } else {
            for (int j = base; j < e; ++j)
                out[j] = bf2f(wbf[j]) * bf2f(wbf[fri[j]]);
        }
    }
    for (int i = gid + 2 * gsz; i < tv4; i += gsz) {
        int base = i * 4;
        if (base + 3 < e) {
            iv4 f = __builtin_nontemporal_load(((const iv4*)fri) + i);
            sv4 h = ((const sv4*)wbf)[i];
            fv4 o;
            o.x = bf2f(h.x) * bf2f(wbf[f.x]);
            o.y = bf2f(h.y) * bf2f(wbf[f.y]);
            o.z = bf2f(h.z) * bf2f(wbf[f.z]);
            o.w = bf2f(h.w) * bf2f(wbf[f.w]);
            __builtin_nontemporal_store(o, ((fv4*)out) + i);
        } else {
            for (int j = base; j < e; ++j)
                out[j] = bf2f(wbf[j]) * bf2f(wbf[fri[j]]);
        }
    }
}

// ---------------- K1: per-node projections (fallback path) -----------------
__global__ void proj_kernel(const fv4* __restrict__ x4, const fv4* __restrict__ W4,
                            float* __restrict__ sl, float* __restrict__ sr, int n) {
    int gid  = blockIdx.x * blockDim.x + threadIdx.x;
    int node = gid >> 5;
    int sub  = gid & 31;
    if (node >= n) return;
    fv4 v  = x4[(size_t)node * 32 + sub];
    fv4 wl = W4[sub];
    fv4 wr = W4[32 + sub];
    float pl = v.x * wl.x + v.y * wl.y + v.z * wl.z + v.w * wl.w;
    float pr = v.x * wr.x + v.y * wr.y + v.z * wr.z + v.w * wr.w;
#pragma unroll
    for (int off = 16; off; off >>= 1) {
        pl += __shfl_xor(pl, off);
        pr += __shfl_xor(pr, off);
    }
    if (sub == 0) { sl[node] = pl; sr[node] = pr; }
}

// ---------------- K2: edge weights -> bf16 (fallback path) -----------------
__global__ __launch_bounds__(256)
void weights_bf_kernel(const int* __restrict__ row, const int* __restrict__ col,
                       const float* __restrict__ sl, const float* __restrict__ sr,
                       unsigned short* __restrict__ wbf, int e) {
    int i = blockIdx.x * blockDim.x + threadIdx.x;
    int base = i * 4;
    if (base + 3 < e) {
        iv4 r = __builtin_nontemporal_load(((const iv4*)row) + i);
        iv4 c = __builtin_nontemporal_load(((const iv4*)col) + i);
        sv4 h;
        h.x = f2bf(sigmoidf_(sl[r.x] + sr[c.x]));
        h.y = f2bf(sigmoidf_(sl[r.y] + sr[c.y]));
        h.z = f2bf(sigmoidf_(sl[r.z] + sr[c.z]));
        h.w = f2bf(sigmoidf_(sl[r.w] + sr[c.w]));
        ((sv4*)wbf)[i] = h;
    } else if (base < e) {
        for (int j = base; j < e; ++j)
            wbf[j] = f2bf(sigmoidf_(sl[row[j]] + sr[col[j]]));
    }
}

// ---------------- K3: gathered product (fallback path) ---------------------
__global__ __launch_bounds__(256)
void final4_kernel(const unsigned short* __restrict__ wbf,
                   const int* __restrict__ fri, float* __restrict__ out, int e) {
    int i = blockIdx.x * blockDim.x + threadIdx.x;
    int base = i * 4;
    if (base + 3 < e) {
        iv4 f = __builtin_nontemporal_load(((const iv4*)fri) + i);
        sv4 h = ((const sv4*)wbf)[i];
        float b0 = bf2f(wbf[f.x]);
        float b1 = bf2f(wbf[f.y]);
        float b2 = bf2f(wbf[f.z]);
        float b3 = bf2f(wbf[f.w]);
        fv4 o;
        o.x = bf2f(h.x) * b0;
        o.y = bf2f(h.y) * b1;
        o.z = bf2f(h.z) * b2;
        o.w = bf2f(h.w) * b3;
        __builtin_nontemporal_store(o, ((fv4*)out) + i);
    } else if (base < e) {
        for (int j = base; j < e; ++j)
            out[j] = bf2f(wbf[j]) * bf2f(wbf[fri[j]]);
    }
}

// ---------------- Fallbacks ------------------------------------------------
__global__ void recompute_kernel(const int* __restrict__ row, const int* __restrict__ col,
                                 const int* __restrict__ fri,
                                 const float* __restrict__ sl, const float* __restrict__ sr,
                                 float* __restrict__ out, int e) {
    int i = blockIdx.x * blockDim.x + threadIdx.x;
    if (i >= e) return;
    int f = fri[i];
    float wa = sigmoidf_(sl[row[i]] + sr[col[i]]);
    float wb = sigmoidf_(sl[row[f]] + sr[col[f]]);
    out[i] = wa * wb;
}

__global__ void naive_kernel(const float* __restrict__ x, const float* __restrict__ W,
                             const int* __restrict__ row, const int* __restrict__ col,
                             const int* __restrict__ fri, float* __restrict__ out, int e) {
    int gid  = blockIdx.x * blockDim.x + threadIdx.x;
    int edge = gid >> 6;
    int lane = gid & 63;
    if (edge >= e) return;
    int f = fri[edge];
    const float2* X = (const float2*)x;
    float2 wl = ((const float2*)W)[lane];
    float2 wr = ((const float2*)W)[64 + lane];
    float2 a1 = X[(size_t)row[edge] * 64 + lane];
    float2 b1 = X[(size_t)col[edge] * 64 + lane];
    float2 a2 = X[(size_t)row[f] * 64 + lane];
    float2 b2 = X[(size_t)col[f] * 64 + lane];
    float p1 = a1.x * wl.x + a1.y * wl.y + b1.x * wr.x + b1.y * wr.y;
    float p2 = a2.x * wl.x + a2.y * wl.y + b2.x * wr.x + b2.y * wr.y;
#pragma unroll
    for (int off = 32; off; off >>= 1) {
        p1 += __shfl_xor(p1, off);
        p2 += __shfl_xor(p2, off);
    }
    if (lane == 0) out[edge] = sigmoidf_(p1) * sigmoidf_(p2);
}

extern "C" void kernel_launch(void* const* d_in, const int* in_sizes, int n_in,
                              void* d_out, int out_size, void* d_ws, size_t ws_size,
                              hipStream_t stream) {
    const float* x   = (const float*)d_in[0];
    const int*   ei  = (const int*)d_in[1];
    const int*   fri = (const int*)d_in[2];
    const float* W   = (const float*)d_in[3];
    float* out = (float*)d_out;

    const int n = in_sizes[0] / CDIM;   // 100000 nodes
    const int e = in_sizes[2];          // 1600000 edges
    const int* row = ei;
    const int* col = ei + e;

    const size_t need_s  = (size_t)2 * n * sizeof(float);
    const size_t need_bf = need_s + (size_t)e * sizeof(unsigned short);

    float* sl = (float*)d_ws;
    float* sr = sl + n;

    const int BS = 256;
    const int tv4 = (e + 3) / 4;
    const long long proj_threads = (long long)n * 32;
    const int proj_grid = (int)((proj_threads + BS - 1) / BS);

    if (ws_size >= need_bf) {
        unsigned short* wbf = (unsigned short*)(sr + n);
        // Plain launch of the persistent fused kernel. Co-residency from
        // capacity slack: 448 blocks at <=2/CU (launch_bounds) into 256 CUs.
        fused_kernel<<<FUSED_GRID, FUSED_BLOCK, 0, stream>>>(
            (const fv4*)x, (const fv4*)W, row, col, fri,
            sl, sr, wbf, out, n, e);
    } else if (ws_size >= need_s) {
        proj_kernel<<<proj_grid, BS, 0, stream>>>((const fv4*)x, (const fv4*)W, sl, sr, n);
        recompute_kernel<<<(e + BS - 1) / BS, BS, 0, stream>>>(row, col, fri, sl, sr, out, e);
    } else {
        long long t = (long long)e * 64;
        naive_kernel<<<(int)((t + BS - 1) / BS), BS, 0, stream>>>(x, W, row, col, fri, out, e);
    }
}